// Round 1
// baseline (443.540 us; speedup 1.0000x reference)
//
#include <hip/hip_runtime.h>
#include <math.h>

#define R_N 4096
#define D_N 4096
#define C_N 20         // foreground classes
#define NCOL 42        // 21 cls + 21 det logit columns
#define IMG_W_F 1216.0f
#define IMG_H_F 800.0f
#define SCORE_TH 0.05f
#define NMS_TH 0.5f
#define TOPK_N 100

// ---- workspace layout (units: 4-byte words) ----
#define LOGITS_WORDS (R_N * NCOL)           // 172032
#define OFF_CTRL    (LOGITS_WORDS)          // 21 ints: cls_count[20], kept_count
#define OFF_DSTAT   (OFF_CTRL + 64)         // 40 f32: dmax[20], dsum[20]
#define OFF_CAND_R  (OFF_DSTAT + 64)        // 20*32 ints
#define OFF_CAND_S  (OFF_CAND_R + 640)      // 20*32 f32
#define OFF_KEPT_I  (OFF_CAND_S + 640)      // 512 ints
#define OFF_KEPT_S  (OFF_KEPT_I + 512)      // 512 f32

// ================= GEMM: logits[r][c] = x[r,:] @ W[:,c]  =================
// grid 512 = 16 row-blocks x 32 k-splits; block: 256 rows x 128 K; thread: 2 rows x 21 cols
#define RB 256
#define KC 128
#define KT 32
__global__ __launch_bounds__(256) void gemm_kernel(
    const float* __restrict__ x, const float* __restrict__ Wc,
    const float* __restrict__ Wd, float* __restrict__ logits) {
  __shared__ float sx[KT * 257];   // transposed [kk][row], pad 257
  __shared__ float sw[KT * 44];    // [kk][c], pad 44
  const int t = threadIdx.x;
  const int bx = blockIdx.x;
  const int r0 = (bx & 15) * RB;
  const int k0 = (bx >> 4) * KC;
  const int rt = t & 127;
  const int cg = t >> 7;           // 0/1 col-group (wave-uniform)
  const int c0 = cg * 21;

  float acc0[21], acc1[21];
#pragma unroll
  for (int c = 0; c < 21; c++) { acc0[c] = 0.f; acc1[c] = 0.f; }

  for (int kt = 0; kt < KC / KT; kt++) {
    const int kb = k0 + kt * KT;
    // stage x tile: 256 rows x 32 k, coalesced float4, store transposed
#pragma unroll
    for (int i = 0; i < 8; i++) {
      int f4 = t + i * 256;
      int row = f4 >> 3, kq = f4 & 7;
      const float4 v = *(const float4*)(x + (size_t)(r0 + row) * D_N + kb + kq * 4);
      sx[(kq * 4 + 0) * 257 + row] = v.x;
      sx[(kq * 4 + 1) * 257 + row] = v.y;
      sx[(kq * 4 + 2) * 257 + row] = v.z;
      sx[(kq * 4 + 3) * 257 + row] = v.w;
    }
    // stage W tile: 32 k x 42 c
    for (int f = t; f < KT * 42; f += 256) {
      int kk = f / 42, c = f - kk * 42;
      int d = kb + kk;
      float wv = (c < 21) ? Wc[(size_t)d * 21 + c] : Wd[(size_t)d * 21 + (c - 21)];
      sw[kk * 44 + c] = wv;
    }
    __syncthreads();
#pragma unroll 4
    for (int kk = 0; kk < KT; kk++) {
      float x0 = sx[kk * 257 + 2 * rt];
      float x1 = sx[kk * 257 + 2 * rt + 1];
#pragma unroll
      for (int c = 0; c < 21; c++) {
        float w = sw[kk * 44 + c0 + c];
        acc0[c] = fmaf(x0, w, acc0[c]);
        acc1[c] = fmaf(x1, w, acc1[c]);
      }
    }
    __syncthreads();
  }
  const int ra = r0 + 2 * rt, rb = ra + 1;
#pragma unroll
  for (int c = 0; c < 21; c++) {
    atomicAdd(&logits[(size_t)ra * NCOL + c0 + c], acc0[c]);
    atomicAdd(&logits[(size_t)rb * NCOL + c0 + c], acc1[c]);
  }
}

// ============ det-softmax column stats (max & sum-exp per class) ============
__global__ __launch_bounds__(256) void detstat_kernel(
    const float* __restrict__ logits, const float* __restrict__ b_det,
    float* __restrict__ dstat) {
  const int c = blockIdx.x;   // 0..19
  const int t = threadIdx.x;
  const float bd = b_det[c];
  __shared__ float redm[4], reds[4];
  float m = -1e30f;
  for (int r = t; r < R_N; r += 256) m = fmaxf(m, logits[r * NCOL + 21 + c] + bd);
  for (int off = 32; off; off >>= 1) m = fmaxf(m, __shfl_down(m, off, 64));
  if ((t & 63) == 0) redm[t >> 6] = m;
  __syncthreads();
  m = fmaxf(fmaxf(redm[0], redm[1]), fmaxf(redm[2], redm[3]));
  float s = 0.f;
  for (int r = t; r < R_N; r += 256) s += expf(logits[r * NCOL + 21 + c] + bd - m);
  for (int off = 32; off; off >>= 1) s += __shfl_down(s, off, 64);
  if ((t & 63) == 0) reds[t >> 6] = s;
  __syncthreads();
  if (t == 0) {
    dstat[c] = m;
    dstat[20 + c] = reds[0] + reds[1] + reds[2] + reds[3];
  }
}

// ====== per-row cls softmax * det softmax; compact candidates > thresh ======
__global__ __launch_bounds__(256) void scores_kernel(
    const float* __restrict__ logits, const float* __restrict__ b_cls,
    const float* __restrict__ b_det, const float* __restrict__ dstat,
    int* __restrict__ cls_count, int* __restrict__ cand_r, float* __restrict__ cand_s) {
  const int r = blockIdx.x * 256 + threadIdx.x;   // 16 blocks -> 4096
  float l[21];
  float m = -1e30f;
#pragma unroll
  for (int c = 0; c < 21; c++) {
    l[c] = logits[(size_t)r * NCOL + c] + b_cls[c];
    m = fmaxf(m, l[c]);
  }
  float s = 0.f;
#pragma unroll
  for (int c = 0; c < 21; c++) { l[c] = expf(l[c] - m); s += l[c]; }
  const float inv = 1.f / s;
  for (int c = 0; c < 20; c++) {
    float det = logits[(size_t)r * NCOL + 21 + c] + b_det[c];
    float dp = expf(det - dstat[c]) / dstat[20 + c];
    float sc = l[c] * inv * dp;
    if (sc > SCORE_TH) {
      int p = atomicAdd(&cls_count[c], 1);
      if (p < 32) { cand_r[c * 32 + p] = r; cand_s[c * 32 + p] = sc; }
    }
  }
}

// ====================== per-class greedy NMS (<=32 cands) ======================
__device__ __forceinline__ void load_clip_box(const float* boxes, int r, float* b) {
  b[0] = fminf(fmaxf(boxes[r * 4 + 0], 0.f), IMG_W_F);
  b[1] = fminf(fmaxf(boxes[r * 4 + 1], 0.f), IMG_H_F);
  b[2] = fminf(fmaxf(boxes[r * 4 + 2], 0.f), IMG_W_F);
  b[3] = fminf(fmaxf(boxes[r * 4 + 3], 0.f), IMG_H_F);
}

__global__ void nms_kernel(const float* __restrict__ boxes,
                           const int* __restrict__ cls_count,
                           const int* __restrict__ cand_r, const float* __restrict__ cand_s,
                           int* __restrict__ kept_count, int* __restrict__ kept_idx,
                           float* __restrict__ kept_s) {
  const int c = threadIdx.x;
  if (c >= 20) return;
  int n = cls_count[c];
  if (n > 32) n = 32;
  float s[32]; int rr[32];
  for (int i = 0; i < n; i++) { s[i] = cand_s[c * 32 + i]; rr[i] = cand_r[c * 32 + i]; }
  // insertion sort: score desc, tie -> row index asc (matches stable argsort(-sc))
  for (int i = 1; i < n; i++) {
    float si = s[i]; int ri = rr[i];
    int j = i - 1;
    while (j >= 0 && (s[j] < si || (s[j] == si && rr[j] > ri))) {
      s[j + 1] = s[j]; rr[j + 1] = rr[j]; j--;
    }
    s[j + 1] = si; rr[j + 1] = ri;
  }
  unsigned supp = 0;
  for (int i = 0; i < n; i++) {
    if (supp & (1u << i)) continue;
    int g = atomicAdd(kept_count, 1);
    if (g < 512) { kept_idx[g] = rr[i] * C_N + c; kept_s[g] = s[i]; }
    float bi[4]; load_clip_box(boxes, rr[i], bi);
    float ai = (bi[2] - bi[0]) * (bi[3] - bi[1]);
    for (int j = i + 1; j < n; j++) {
      if (supp & (1u << j)) continue;
      float bj[4]; load_clip_box(boxes, rr[j], bj);
      float aj = (bj[2] - bj[0]) * (bj[3] - bj[1]);
      float lx = fmaxf(bi[0], bj[0]), ly = fmaxf(bi[1], bj[1]);
      float rx = fminf(bi[2], bj[2]), ry = fminf(bi[3], bj[3]);
      float w = fmaxf(rx - lx, 0.f), h = fmaxf(ry - ly, 0.f);
      float inter = w * h;
      float iou = inter / (ai + aj - inter + 1e-9f);
      if (iou > NMS_TH) supp |= (1u << j);
    }
  }
}

// =================== final top-100 with jax.lax.top_k tie rules ===================
__global__ __launch_bounds__(128) void finalize_kernel(
    const float* __restrict__ boxes, const int* __restrict__ kept_count,
    const int* __restrict__ kept_idx, const float* __restrict__ kept_s,
    float* __restrict__ out) {
  __shared__ float sval[TOPK_N];
  __shared__ int sidx[TOPK_N];
  const int t = threadIdx.x;
  int m = *kept_count;
  if (m > 512) m = 512;
  if (t < TOPK_N) { sval[t] = 0.f; sidx[t] = 0; }
  __syncthreads();
  // rank each kept entry: (score desc, flat idx asc)
  for (int i = t; i < m; i += 128) {
    float si = kept_s[i]; int xi = kept_idx[i];
    int rank = 0;
    for (int j = 0; j < m; j++) {
      float sj = kept_s[j]; int xj = kept_idx[j];
      if (sj > si || (sj == si && xj < xi)) rank++;
    }
    if (rank < TOPK_N) { sval[rank] = si; sidx[rank] = xi; }
  }
  __syncthreads();
  if (t == 0) {
    int f = m < TOPK_N ? m : TOPK_N;
    int cur = 0;
    for (int slot = f; slot < TOPK_N; slot++) {
      for (;;) {
        bool member = false;
        for (int j = 0; j < m; j++)
          if (kept_idx[j] == cur) { member = true; break; }
        if (!member) break;
        cur++;
      }
      sval[slot] = 0.f;
      sidx[slot] = cur;
      cur++;
    }
  }
  __syncthreads();
  if (t < TOPK_N) {
    int idx = sidx[t];
    int prop = idx / C_N;
    int cls = idx - prop * C_N;
    float b[4]; load_clip_box(boxes, prop, b);
    out[t] = sval[t];                       // top_vals
    out[TOPK_N + t * 4 + 0] = b[0];         // top_boxes
    out[TOPK_N + t * 4 + 1] = b[1];
    out[TOPK_N + t * 4 + 2] = b[2];
    out[TOPK_N + t * 4 + 3] = b[3];
    out[TOPK_N * 5 + t] = (float)cls;       // top_cls
  }
}

extern "C" void kernel_launch(void* const* d_in, const int* in_sizes, int n_in,
                              void* d_out, int out_size, void* d_ws, size_t ws_size,
                              hipStream_t stream) {
  const float* x     = (const float*)d_in[0];
  const float* boxes = (const float*)d_in[1];
  const float* W_cls = (const float*)d_in[2];
  const float* b_cls = (const float*)d_in[3];
  const float* W_det = (const float*)d_in[4];
  const float* b_det = (const float*)d_in[5];
  float* out = (float*)d_out;

  float* ws = (float*)d_ws;
  float* logits    = ws;
  int*   cls_count = (int*)(ws + OFF_CTRL);        // 20 ints
  int*   kept_cnt  = (int*)(ws + OFF_CTRL) + 20;   // 1 int
  float* dstat     = ws + OFF_DSTAT;
  int*   cand_r    = (int*)(ws + OFF_CAND_R);
  float* cand_s    = ws + OFF_CAND_S;
  int*   kept_idx  = (int*)(ws + OFF_KEPT_I);
  float* kept_s    = ws + OFF_KEPT_S;

  // zero logits + counters (ws is poisoned 0xAA before every timed launch)
  hipMemsetAsync(d_ws, 0, (size_t)(LOGITS_WORDS + 32) * 4, stream);

  gemm_kernel<<<512, 256, 0, stream>>>(x, W_cls, W_det, logits);
  detstat_kernel<<<20, 256, 0, stream>>>(logits, b_det, dstat);
  scores_kernel<<<16, 256, 0, stream>>>(logits, b_cls, b_det, dstat,
                                        cls_count, cand_r, cand_s);
  nms_kernel<<<1, 64, 0, stream>>>(boxes, cls_count, cand_r, cand_s,
                                   kept_cnt, kept_idx, kept_s);
  finalize_kernel<<<1, 128, 0, stream>>>(boxes, kept_cnt, kept_idx, kept_s, out);
}

// Round 2
// 232.785 us; speedup vs baseline: 1.9054x; 1.9054x over previous
//
#include <hip/hip_runtime.h>
#include <math.h>

#define R_N 4096
#define D_N 4096
#define C_N 20         // foreground classes
#define NCOL 42        // 21 cls + 21 det logit columns
#define IMG_W_F 1216.0f
#define IMG_H_F 800.0f
#define SCORE_TH 0.05f
#define NMS_TH 0.5f
#define TOPK_N 100

#define NSPLIT 16      // k-splits
#define RB 256         // rows per block
#define KC 256         // K per split
#define KT 32          // K per LDS tile

// ---- workspace layout (units: 4-byte words) ----
#define PARTIAL_WORDS (NSPLIT * R_N * NCOL)       // 16*172032 = 2752512
#define LOGITS_OFF   (PARTIAL_WORDS)
#define LOGITS_WORDS (R_N * NCOL)                 // 172032
#define OFF_CTRL    (LOGITS_OFF + LOGITS_WORDS)   // 21 ints: cls_count[20], kept_count
#define OFF_DSTAT   (OFF_CTRL + 64)               // 40 f32: dmax[20], dsum[20]
#define OFF_CAND_R  (OFF_DSTAT + 64)              // 20*32 ints
#define OFF_CAND_S  (OFF_CAND_R + 640)            // 20*32 f32
#define OFF_KEPT_I  (OFF_CAND_S + 640)            // 512 ints
#define OFF_KEPT_S  (OFF_KEPT_I + 512)            // 512 f32

// ================= GEMM: partial[s][r][c] = x[r, ks..ks+KC) @ W[.., c] =================
// grid 256 = 16 row-blocks x 16 k-splits; block: 256 rows x KC K; thread: 2 rows x 21 cols
__global__ __launch_bounds__(256) void gemm_kernel(
    const float* __restrict__ x, const float* __restrict__ Wc,
    const float* __restrict__ Wd, float* __restrict__ partial) {
  __shared__ float sx[KT * 257];   // transposed [kk][row], pad 257
  __shared__ float sw[KT * 44];    // [kk][c], pad 44
  const int t = threadIdx.x;
  const int bx = blockIdx.x;
  const int r0 = (bx & 15) * RB;
  const int split = bx >> 4;
  const int k0 = split * KC;
  const int rt = t & 127;
  const int cg = t >> 7;           // 0/1 col-group (wave-uniform: waves 0,1 -> 0; 2,3 -> 1)
  const int c0 = cg * 21;

  float acc0[21], acc1[21];
#pragma unroll
  for (int c = 0; c < 21; c++) { acc0[c] = 0.f; acc1[c] = 0.f; }

  for (int kt = 0; kt < KC / KT; kt++) {
    const int kb = k0 + kt * KT;
    // stage x tile: 256 rows x 32 k, coalesced float4, store transposed
#pragma unroll
    for (int i = 0; i < 8; i++) {
      int f4 = t + i * 256;
      int row = f4 >> 3, kq = f4 & 7;
      const float4 v = *(const float4*)(x + (size_t)(r0 + row) * D_N + kb + kq * 4);
      sx[(kq * 4 + 0) * 257 + row] = v.x;
      sx[(kq * 4 + 1) * 257 + row] = v.y;
      sx[(kq * 4 + 2) * 257 + row] = v.z;
      sx[(kq * 4 + 3) * 257 + row] = v.w;
    }
    // stage W tile: 32 k x 42 c
    for (int f = t; f < KT * 42; f += 256) {
      int kk = f / 42, c = f - kk * 42;
      int d = kb + kk;
      float wv = (c < 21) ? Wc[(size_t)d * 21 + c] : Wd[(size_t)d * 21 + (c - 21)];
      sw[kk * 44 + c] = wv;
    }
    __syncthreads();
#pragma unroll 4
    for (int kk = 0; kk < KT; kk++) {
      float x0 = sx[kk * 257 + 2 * rt];
      float x1 = sx[kk * 257 + 2 * rt + 1];
#pragma unroll
      for (int c = 0; c < 21; c++) {
        float w = sw[kk * 44 + c0 + c];
        acc0[c] = fmaf(x0, w, acc0[c]);
        acc1[c] = fmaf(x1, w, acc1[c]);
      }
    }
    __syncthreads();
  }
  // plain stores to this split's private region — no atomics
  const int ra = r0 + 2 * rt, rb = ra + 1;
  float* p = partial + (size_t)split * (R_N * NCOL);
#pragma unroll
  for (int c = 0; c < 21; c++) {
    p[(size_t)ra * NCOL + c0 + c] = acc0[c];
    p[(size_t)rb * NCOL + c0 + c] = acc1[c];
  }
}

// ============== reduce partials: logits[r][c] = sum_s partial[s][r][c] ==============
__global__ __launch_bounds__(256) void reduce_kernel(
    const float* __restrict__ partial, float* __restrict__ logits) {
  const int i = blockIdx.x * 256 + threadIdx.x;   // 672 blocks -> 172032
  float s = 0.f;
#pragma unroll
  for (int sp = 0; sp < NSPLIT; sp++) s += partial[(size_t)sp * (R_N * NCOL) + i];
  logits[i] = s;
}

// ============ det-softmax column stats (max & sum-exp per class) ============
__global__ __launch_bounds__(1024) void detstat_kernel(
    const float* __restrict__ logits, const float* __restrict__ b_det,
    float* __restrict__ dstat) {
  const int c = blockIdx.x;   // 0..19
  const int t = threadIdx.x;
  const float bd = b_det[c];
  __shared__ float redm[16], reds[16];
  float m = -1e30f;
  for (int r = t; r < R_N; r += 1024) m = fmaxf(m, logits[r * NCOL + 21 + c] + bd);
  for (int off = 32; off; off >>= 1) m = fmaxf(m, __shfl_down(m, off, 64));
  if ((t & 63) == 0) redm[t >> 6] = m;
  __syncthreads();
  m = -1e30f;
#pragma unroll
  for (int i = 0; i < 16; i++) m = fmaxf(m, redm[i]);
  float s = 0.f;
  for (int r = t; r < R_N; r += 1024) s += expf(logits[r * NCOL + 21 + c] + bd - m);
  for (int off = 32; off; off >>= 1) s += __shfl_down(s, off, 64);
  if ((t & 63) == 0) reds[t >> 6] = s;
  __syncthreads();
  if (t == 0) {
    float ss = 0.f;
#pragma unroll
    for (int i = 0; i < 16; i++) ss += reds[i];
    dstat[c] = m;
    dstat[20 + c] = ss;
  }
}

// ====== per-row cls softmax * det softmax; compact candidates > thresh ======
__global__ __launch_bounds__(256) void scores_kernel(
    const float* __restrict__ logits, const float* __restrict__ b_cls,
    const float* __restrict__ b_det, const float* __restrict__ dstat,
    int* __restrict__ cls_count, int* __restrict__ cand_r, float* __restrict__ cand_s) {
  const int r = blockIdx.x * 256 + threadIdx.x;   // 16 blocks -> 4096
  float l[21];
  float m = -1e30f;
#pragma unroll
  for (int c = 0; c < 21; c++) {
    l[c] = logits[(size_t)r * NCOL + c] + b_cls[c];
    m = fmaxf(m, l[c]);
  }
  float s = 0.f;
#pragma unroll
  for (int c = 0; c < 21; c++) { l[c] = expf(l[c] - m); s += l[c]; }
  const float inv = 1.f / s;
  for (int c = 0; c < 20; c++) {
    float det = logits[(size_t)r * NCOL + 21 + c] + b_det[c];
    float dp = expf(det - dstat[c]) / dstat[20 + c];
    float sc = l[c] * inv * dp;
    if (sc > SCORE_TH) {
      int p = atomicAdd(&cls_count[c], 1);
      if (p < 32) { cand_r[c * 32 + p] = r; cand_s[c * 32 + p] = sc; }
    }
  }
}

// ====================== per-class greedy NMS (<=32 cands) ======================
__device__ __forceinline__ void load_clip_box(const float* boxes, int r, float* b) {
  b[0] = fminf(fmaxf(boxes[r * 4 + 0], 0.f), IMG_W_F);
  b[1] = fminf(fmaxf(boxes[r * 4 + 1], 0.f), IMG_H_F);
  b[2] = fminf(fmaxf(boxes[r * 4 + 2], 0.f), IMG_W_F);
  b[3] = fminf(fmaxf(boxes[r * 4 + 3], 0.f), IMG_H_F);
}

__global__ void nms_kernel(const float* __restrict__ boxes,
                           const int* __restrict__ cls_count,
                           const int* __restrict__ cand_r, const float* __restrict__ cand_s,
                           int* __restrict__ kept_count, int* __restrict__ kept_idx,
                           float* __restrict__ kept_s) {
  const int c = threadIdx.x;
  if (c >= 20) return;
  int n = cls_count[c];
  if (n > 32) n = 32;
  float s[32]; int rr[32];
  for (int i = 0; i < n; i++) { s[i] = cand_s[c * 32 + i]; rr[i] = cand_r[c * 32 + i]; }
  // insertion sort: score desc, tie -> row index asc (matches stable argsort(-sc))
  for (int i = 1; i < n; i++) {
    float si = s[i]; int ri = rr[i];
    int j = i - 1;
    while (j >= 0 && (s[j] < si || (s[j] == si && rr[j] > ri))) {
      s[j + 1] = s[j]; rr[j + 1] = rr[j]; j--;
    }
    s[j + 1] = si; rr[j + 1] = ri;
  }
  unsigned supp = 0;
  for (int i = 0; i < n; i++) {
    if (supp & (1u << i)) continue;
    int g = atomicAdd(kept_count, 1);
    if (g < 512) { kept_idx[g] = rr[i] * C_N + c; kept_s[g] = s[i]; }
    float bi[4]; load_clip_box(boxes, rr[i], bi);
    float ai = (bi[2] - bi[0]) * (bi[3] - bi[1]);
    for (int j = i + 1; j < n; j++) {
      if (supp & (1u << j)) continue;
      float bj[4]; load_clip_box(boxes, rr[j], bj);
      float aj = (bj[2] - bj[0]) * (bj[3] - bj[1]);
      float lx = fmaxf(bi[0], bj[0]), ly = fmaxf(bi[1], bj[1]);
      float rx = fminf(bi[2], bj[2]), ry = fminf(bi[3], bj[3]);
      float w = fmaxf(rx - lx, 0.f), h = fmaxf(ry - ly, 0.f);
      float inter = w * h;
      float iou = inter / (ai + aj - inter + 1e-9f);
      if (iou > NMS_TH) supp |= (1u << j);
    }
  }
}

// =================== final top-100 with jax.lax.top_k tie rules ===================
__global__ __launch_bounds__(128) void finalize_kernel(
    const float* __restrict__ boxes, const int* __restrict__ kept_count,
    const int* __restrict__ kept_idx, const float* __restrict__ kept_s,
    float* __restrict__ out) {
  __shared__ float sval[TOPK_N];
  __shared__ int sidx[TOPK_N];
  const int t = threadIdx.x;
  int m = *kept_count;
  if (m > 512) m = 512;
  if (t < TOPK_N) { sval[t] = 0.f; sidx[t] = 0; }
  __syncthreads();
  // rank each kept entry: (score desc, flat idx asc)
  for (int i = t; i < m; i += 128) {
    float si = kept_s[i]; int xi = kept_idx[i];
    int rank = 0;
    for (int j = 0; j < m; j++) {
      float sj = kept_s[j]; int xj = kept_idx[j];
      if (sj > si || (sj == si && xj < xi)) rank++;
    }
    if (rank < TOPK_N) { sval[rank] = si; sidx[rank] = xi; }
  }
  __syncthreads();
  if (t == 0) {
    int f = m < TOPK_N ? m : TOPK_N;
    int cur = 0;
    for (int slot = f; slot < TOPK_N; slot++) {
      for (;;) {
        bool member = false;
        for (int j = 0; j < m; j++)
          if (kept_idx[j] == cur) { member = true; break; }
        if (!member) break;
        cur++;
      }
      sval[slot] = 0.f;
      sidx[slot] = cur;
      cur++;
    }
  }
  __syncthreads();
  if (t < TOPK_N) {
    int idx = sidx[t];
    int prop = idx / C_N;
    int cls = idx - prop * C_N;
    float b[4]; load_clip_box(boxes, prop, b);
    out[t] = sval[t];                       // top_vals
    out[TOPK_N + t * 4 + 0] = b[0];         // top_boxes
    out[TOPK_N + t * 4 + 1] = b[1];
    out[TOPK_N + t * 4 + 2] = b[2];
    out[TOPK_N + t * 4 + 3] = b[3];
    out[TOPK_N * 5 + t] = (float)cls;       // top_cls
  }
}

extern "C" void kernel_launch(void* const* d_in, const int* in_sizes, int n_in,
                              void* d_out, int out_size, void* d_ws, size_t ws_size,
                              hipStream_t stream) {
  const float* x     = (const float*)d_in[0];
  const float* boxes = (const float*)d_in[1];
  const float* W_cls = (const float*)d_in[2];
  const float* b_cls = (const float*)d_in[3];
  const float* W_det = (const float*)d_in[4];
  const float* b_det = (const float*)d_in[5];
  float* out = (float*)d_out;

  float* ws = (float*)d_ws;
  float* partial   = ws;
  float* logits    = ws + LOGITS_OFF;
  int*   cls_count = (int*)(ws + OFF_CTRL);        // 20 ints
  int*   kept_cnt  = (int*)(ws + OFF_CTRL) + 20;   // 1 int
  float* dstat     = ws + OFF_DSTAT;
  int*   cand_r    = (int*)(ws + OFF_CAND_R);
  float* cand_s    = ws + OFF_CAND_S;
  int*   kept_idx  = (int*)(ws + OFF_KEPT_I);
  float* kept_s    = ws + OFF_KEPT_S;

  // zero only the counters (21 ints); everything else is write-before-read
  hipMemsetAsync((void*)cls_count, 0, 32 * 4, stream);

  gemm_kernel<<<256, 256, 0, stream>>>(x, W_cls, W_det, partial);
  reduce_kernel<<<LOGITS_WORDS / 256, 256, 0, stream>>>(partial, logits);
  detstat_kernel<<<20, 1024, 0, stream>>>(logits, b_det, dstat);
  scores_kernel<<<16, 256, 0, stream>>>(logits, b_cls, b_det, dstat,
                                        cls_count, cand_r, cand_s);
  nms_kernel<<<1, 64, 0, stream>>>(boxes, cls_count, cand_r, cand_s,
                                   kept_cnt, kept_idx, kept_s);
  finalize_kernel<<<1, 128, 0, stream>>>(boxes, kept_cnt, kept_idx, kept_s, out);
}

// Round 3
// 154.833 us; speedup vs baseline: 2.8646x; 1.5035x over previous
//
#include <hip/hip_runtime.h>
#include <math.h>

#define R_N 4096
#define D_N 4096
#define C_N 20
#define IMG_W_F 1216.0f
#define IMG_H_F 800.0f
#define SCORE_TH 0.05f
#define NMS_TH 0.5f
#define TOPK_N 100

#define NSPLIT 16
#define NCOLP 48                 // 21 cls + 21 det + 6 zero pad
#define KC 256                   // K per split
#define RB 64                    // rows per block

// ---- workspace layout (units: 4-byte words) ----
#define WT_WORDS   (NCOLP * D_N / 2)                 // 48x4096 bf16 = 98304 words
#define PART_OFF   (WT_WORDS)
#define PART_STRIDE (NCOLP * R_N)                    // 196608 words per split
#define PART_WORDS (NSPLIT * PART_STRIDE)            // 3145728
#define LOGT_OFF   (PART_OFF + PART_WORDS)           // logits_T [42][4096]
#define LOGT_WORDS (42 * R_N)
#define DSUM_OFF   (LOGT_OFF + LOGT_WORDS)           // 32 words
// total ~13.03 MB

typedef short bf16x8 __attribute__((ext_vector_type(8)));
typedef float f32x4  __attribute__((ext_vector_type(4)));

__device__ __forceinline__ unsigned short f2bf(float f) {
  union { float f; unsigned u; } v; v.f = f;
  unsigned r = (v.u + 0x7FFFu + ((v.u >> 16) & 1u)) >> 16;
  return (unsigned short)r;
}

// ============ W transpose + bf16 convert: W_T[c][k], c<21 cls, 21..41 det, 42..47 zero ============
__global__ __launch_bounds__(256) void wT_kernel(
    const float* __restrict__ Wc, const float* __restrict__ Wd,
    unsigned short* __restrict__ W_T, float* __restrict__ dsum) {
  const int k = blockIdx.x * 256 + threadIdx.x;   // 16 blocks -> 4096
#pragma unroll
  for (int c = 0; c < 21; c++)
    W_T[c * D_N + k] = f2bf(Wc[(size_t)k * 21 + c]);
#pragma unroll
  for (int c = 0; c < 21; c++)
    W_T[(21 + c) * D_N + k] = f2bf(Wd[(size_t)k * 21 + c]);
#pragma unroll
  for (int c = 42; c < 48; c++) W_T[c * D_N + k] = 0;
  if (blockIdx.x == 0 && threadIdx.x < 32) dsum[threadIdx.x] = 0.f;
}

// ================= MFMA GEMM: partial[s][c][r] = x[r, ks:ks+256) @ W[:, c] =================
// grid 1024 = 64 row-blocks(64 rows) x 16 splits; 256 thr = 4 waves; wave w -> m-tile w
__global__ __launch_bounds__(256) void gemm_kernel(
    const float* __restrict__ x, const unsigned short* __restrict__ W_T,
    float* __restrict__ partial) {
  __shared__ char lds_raw[64 * 264 * 2 + NCOLP * 264 * 2];   // x-tile 33792 B + W-tile 25344 B
  unsigned short* xl = (unsigned short*)lds_raw;             // [row][264]
  unsigned short* wl = (unsigned short*)(lds_raw + 64 * 264 * 2); // [col][264]

  const int t = threadIdx.x;
  const int bx = blockIdx.x;
  const int r0 = (bx & 63) * RB;
  const int split = bx >> 6;
  const int k0 = split * KC;

  // ---- stage x tile: 64 rows x 256 k, fp32 -> bf16 ----
#pragma unroll
  for (int i = 0; i < 16; i++) {
    int f = t + i * 256;
    int row = f >> 6, kq = f & 63;
    const float4 v = *(const float4*)(x + (size_t)(r0 + row) * D_N + k0 + kq * 4);
    unsigned lo = (unsigned)f2bf(v.x) | ((unsigned)f2bf(v.y) << 16);
    unsigned hi = (unsigned)f2bf(v.z) | ((unsigned)f2bf(v.w) << 16);
    uint2 p; p.x = lo; p.y = hi;
    *(uint2*)(xl + row * 264 + kq * 4) = p;
  }
  // ---- stage W tile: 48 cols x 256 k bf16, coalesced uint loads ----
  const unsigned* wt32 = (const unsigned*)W_T;   // [48][2048] uints
#pragma unroll
  for (int i = 0; i < 24; i++) {
    int e = t + i * 256;
    int c = e >> 7, kw = e & 127;
    unsigned v = wt32[c * (D_N / 2) + (k0 >> 1) + kw];
    *(unsigned*)(wl + c * 264 + kw * 2) = v;
  }
  __syncthreads();

  // ---- MFMA: wave w computes rows [w*16, w*16+16) x 48 cols ----
  const int l = t & 63, w = t >> 6;
  const int r16 = l & 15, q = l >> 4;
  f32x4 acc0 = {0.f, 0.f, 0.f, 0.f};
  f32x4 acc1 = {0.f, 0.f, 0.f, 0.f};
  f32x4 acc2 = {0.f, 0.f, 0.f, 0.f};
  const unsigned short* ap = xl + (w * 16 + r16) * 264 + q * 8;
  const unsigned short* bp0 = wl + (0  + r16) * 264 + q * 8;
  const unsigned short* bp1 = wl + (16 + r16) * 264 + q * 8;
  const unsigned short* bp2 = wl + (32 + r16) * 264 + q * 8;
#pragma unroll
  for (int s = 0; s < 8; s++) {
    bf16x8 af = *(const bf16x8*)(ap + s * 32);
    acc0 = __builtin_amdgcn_mfma_f32_16x16x32_bf16(af, *(const bf16x8*)(bp0 + s * 32), acc0, 0, 0, 0);
    acc1 = __builtin_amdgcn_mfma_f32_16x16x32_bf16(af, *(const bf16x8*)(bp1 + s * 32), acc1, 0, 0, 0);
    acc2 = __builtin_amdgcn_mfma_f32_16x16x32_bf16(af, *(const bf16x8*)(bp2 + s * 32), acc2, 0, 0, 0);
  }
  __syncthreads();

  // ---- transpose D-frags through LDS: clds[col][68] -> coalesced [c][r] stores ----
  float* cl = (float*)lds_raw;   // 48 x 68 floats = 13056 B (overlays x-tile)
  // lane holds D[row = w*16 + q*4 + reg][col = nt*16 + r16]
  *(f32x4*)(cl + (0  + r16) * 68 + w * 16 + q * 4) = acc0;
  *(f32x4*)(cl + (16 + r16) * 68 + w * 16 + q * 4) = acc1;
  *(f32x4*)(cl + (32 + r16) * 68 + w * 16 + q * 4) = acc2;
  __syncthreads();
  float* p = partial + (size_t)split * PART_STRIDE;
#pragma unroll
  for (int i = 0; i < 3; i++) {
    int e = t + i * 256;
    int c = e >> 4, rq = e & 15;
    f32x4 v = *(const f32x4*)(cl + c * 68 + rq * 4);
    *(f32x4*)(p + (size_t)c * R_N + r0 + rq * 4) = v;
  }
}

// ====== reduce partials -> logits_T[c][r]; det cols also accumulate sum-exp into dsum ======
__global__ __launch_bounds__(256) void reduce_kernel(
    const float* __restrict__ partial, const float* __restrict__ b_det,
    float* __restrict__ logits_T, float* __restrict__ dsum) {
  const int bx = blockIdx.x;          // 168 = 42 cols x 4 row-chunks
  const int c = bx >> 2;
  const int rc = bx & 3;
  const int t = threadIdx.x;
  float v[4];
#pragma unroll
  for (int j = 0; j < 4; j++) {
    int r = rc * 1024 + t + j * 256;
    float s = 0.f;
#pragma unroll
    for (int sp = 0; sp < NSPLIT; sp++)
      s += partial[(size_t)sp * PART_STRIDE + (size_t)c * R_N + r];
    v[j] = s;
    logits_T[(size_t)c * R_N + r] = s;
  }
  if (c >= 21 && c < 41) {
    const int cd = c - 21;
    const float bd = b_det[cd];
    float loc = expf(v[0] + bd) + expf(v[1] + bd) + expf(v[2] + bd) + expf(v[3] + bd);
    for (int off = 32; off; off >>= 1) loc += __shfl_down(loc, off, 64);
    __shared__ float red[4];
    if ((t & 63) == 0) red[t >> 6] = loc;
    __syncthreads();
    if (t == 0) atomicAdd(&dsum[cd], red[0] + red[1] + red[2] + red[3]);
  }
}

// =================== fused tail: scores -> per-class NMS -> top-100 ===================
__device__ __forceinline__ void load_clip_box(const float* boxes, int r, float* b) {
  b[0] = fminf(fmaxf(boxes[r * 4 + 0], 0.f), IMG_W_F);
  b[1] = fminf(fmaxf(boxes[r * 4 + 1], 0.f), IMG_H_F);
  b[2] = fminf(fmaxf(boxes[r * 4 + 2], 0.f), IMG_W_F);
  b[3] = fminf(fmaxf(boxes[r * 4 + 3], 0.f), IMG_H_F);
}

__global__ __launch_bounds__(1024) void tail_kernel(
    const float* __restrict__ logits_T, const float* __restrict__ b_cls,
    const float* __restrict__ b_det, const float* __restrict__ dsum,
    const float* __restrict__ boxes, float* __restrict__ out) {
  __shared__ int   s_cnt[20];
  __shared__ int   s_cr[20 * 32];
  __shared__ float s_cs[20 * 32];
  __shared__ int   s_kc;
  __shared__ int   s_ki[512];
  __shared__ float s_ks[512];
  __shared__ float sval[TOPK_N];
  __shared__ int   sidx[TOPK_N];
  const int t = threadIdx.x;
  if (t < 20) s_cnt[t] = 0;
  if (t == 0) s_kc = 0;
  if (t < TOPK_N) { sval[t] = 0.f; sidx[t] = 0; }
  __syncthreads();

  // ---- phase A: scores + candidate compaction ----
#pragma unroll
  for (int j = 0; j < 4; j++) {
    const int r = t + j * 1024;
    float l[21];
    float m = -1e30f;
#pragma unroll
    for (int c = 0; c < 21; c++) {
      l[c] = logits_T[(size_t)c * R_N + r] + b_cls[c];
      m = fmaxf(m, l[c]);
    }
    float s = 0.f;
#pragma unroll
    for (int c = 0; c < 21; c++) { l[c] = expf(l[c] - m); s += l[c]; }
    const float inv = 1.f / s;
    for (int c = 0; c < 20; c++) {
      float ld = logits_T[(size_t)(21 + c) * R_N + r] + b_det[c];
      float sc = l[c] * inv * expf(ld) / dsum[c];
      if (sc > SCORE_TH) {
        int p = atomicAdd(&s_cnt[c], 1);
        if (p < 32) { s_cr[c * 32 + p] = r; s_cs[c * 32 + p] = sc; }
      }
    }
  }
  __syncthreads();

  // ---- phase B: per-class greedy NMS (threads 0..19) ----
  if (t < 20) {
    const int c = t;
    int n = s_cnt[c]; if (n > 32) n = 32;
    float s[32]; int rr[32];
    for (int i = 0; i < n; i++) { s[i] = s_cs[c * 32 + i]; rr[i] = s_cr[c * 32 + i]; }
    for (int i = 1; i < n; i++) {            // score desc, tie -> row asc
      float si = s[i]; int ri = rr[i];
      int j = i - 1;
      while (j >= 0 && (s[j] < si || (s[j] == si && rr[j] > ri))) {
        s[j + 1] = s[j]; rr[j + 1] = rr[j]; j--;
      }
      s[j + 1] = si; rr[j + 1] = ri;
    }
    unsigned supp = 0;
    for (int i = 0; i < n; i++) {
      if (supp & (1u << i)) continue;
      int g = atomicAdd(&s_kc, 1);
      if (g < 512) { s_ki[g] = rr[i] * C_N + c; s_ks[g] = s[i]; }
      float bi[4]; load_clip_box(boxes, rr[i], bi);
      float ai = (bi[2] - bi[0]) * (bi[3] - bi[1]);
      for (int j = i + 1; j < n; j++) {
        if (supp & (1u << j)) continue;
        float bj[4]; load_clip_box(boxes, rr[j], bj);
        float aj = (bj[2] - bj[0]) * (bj[3] - bj[1]);
        float lx = fmaxf(bi[0], bj[0]), ly = fmaxf(bi[1], bj[1]);
        float rx = fminf(bi[2], bj[2]), ry = fminf(bi[3], bj[3]);
        float wdt = fmaxf(rx - lx, 0.f), hgt = fmaxf(ry - ly, 0.f);
        float inter = wdt * hgt;
        float iou = inter / (ai + aj - inter + 1e-9f);
        if (iou > NMS_TH) supp |= (1u << j);
      }
    }
  }
  __syncthreads();

  // ---- phase C: top-100 with jax.lax.top_k tie rules ----
  int m = s_kc; if (m > 512) m = 512;
  for (int i = t; i < m; i += 1024) {
    float si = s_ks[i]; int xi = s_ki[i];
    int rank = 0;
    for (int j = 0; j < m; j++) {
      float sj = s_ks[j]; int xj = s_ki[j];
      if (sj > si || (sj == si && xj < xi)) rank++;
    }
    if (rank < TOPK_N) { sval[rank] = si; sidx[rank] = xi; }
  }
  __syncthreads();
  if (t == 0) {
    int f = m < TOPK_N ? m : TOPK_N;
    int cur = 0;
    for (int slot = f; slot < TOPK_N; slot++) {
      for (;;) {
        bool member = false;
        for (int j = 0; j < m; j++)
          if (s_ki[j] == cur) { member = true; break; }
        if (!member) break;
        cur++;
      }
      sval[slot] = 0.f;
      sidx[slot] = cur;
      cur++;
    }
  }
  __syncthreads();
  if (t < TOPK_N) {
    int idx = sidx[t];
    int prop = idx / C_N;
    int cls = idx - prop * C_N;
    float b[4]; load_clip_box(boxes, prop, b);
    out[t] = sval[t];
    out[TOPK_N + t * 4 + 0] = b[0];
    out[TOPK_N + t * 4 + 1] = b[1];
    out[TOPK_N + t * 4 + 2] = b[2];
    out[TOPK_N + t * 4 + 3] = b[3];
    out[TOPK_N * 5 + t] = (float)cls;
  }
}

extern "C" void kernel_launch(void* const* d_in, const int* in_sizes, int n_in,
                              void* d_out, int out_size, void* d_ws, size_t ws_size,
                              hipStream_t stream) {
  const float* x     = (const float*)d_in[0];
  const float* boxes = (const float*)d_in[1];
  const float* W_cls = (const float*)d_in[2];
  const float* b_cls = (const float*)d_in[3];
  const float* W_det = (const float*)d_in[4];
  const float* b_det = (const float*)d_in[5];
  float* out = (float*)d_out;

  float* ws = (float*)d_ws;
  unsigned short* W_T = (unsigned short*)ws;          // 48x4096 bf16
  float* partial  = ws + PART_OFF;
  float* logits_T = ws + LOGT_OFF;
  float* dsum     = ws + DSUM_OFF;

  wT_kernel    <<<16,   256, 0, stream>>>(W_cls, W_det, W_T, dsum);
  gemm_kernel  <<<1024, 256, 0, stream>>>(x, W_T, partial);
  reduce_kernel<<<168,  256, 0, stream>>>(partial, b_det, logits_T, dsum);
  tail_kernel  <<<1,   1024, 0, stream>>>(logits_T, b_cls, b_det, dsum, boxes, out);
}

// Round 4
// 139.956 us; speedup vs baseline: 3.1691x; 1.1063x over previous
//
#include <hip/hip_runtime.h>
#include <math.h>

#define R_N 4096
#define D_N 4096
#define C_N 20
#define IMG_W_F 1216.0f
#define IMG_H_F 800.0f
#define SCORE_TH 0.05f
#define NMS_TH 0.5f
#define TOPK_N 100

#define NSPLIT 8
#define NCOLP 48                 // 21 cls + 21 det + 6 zero pad
#define KC 512                   // K per split
#define KTILE 256                // K per LDS stage
#define RB 64                    // rows per block

// ---- workspace layout (units: 4-byte words) ----
#define WT_WORDS   (NCOLP * D_N / 2)                 // 48x4096 bf16 = 98304 words
#define PART_OFF   (WT_WORDS)
#define PART_STRIDE (NCOLP * R_N)                    // 196608 words per split
#define PART_WORDS (NSPLIT * PART_STRIDE)            // 1572864
#define LOGT_OFF   (PART_OFF + PART_WORDS)           // logits_T [42][4096]
#define LOGT_WORDS (42 * R_N)
#define CTRL_OFF   (LOGT_OFF + LOGT_WORDS)           // dsum[20] | cls_count[20] | pad -> 64 words
#define CAND_R_OFF (CTRL_OFF + 64)                   // 20*32 ints
#define CAND_S_OFF (CAND_R_OFF + 640)                // 20*32 f32
// total ~7.4 MB

typedef short bf16x8 __attribute__((ext_vector_type(8)));
typedef float f32x4  __attribute__((ext_vector_type(4)));

__device__ __forceinline__ unsigned short f2bf(float f) {
  union { float f; unsigned u; } v; v.f = f;
  unsigned r = (v.u + 0x7FFFu + ((v.u >> 16) & 1u)) >> 16;
  return (unsigned short)r;
}
__device__ __forceinline__ float fexp(float x) { return __expf(x); }

// ============ W transpose + bf16 convert; also zero ctrl words ============
__global__ __launch_bounds__(256) void wT_kernel(
    const float* __restrict__ Wc, const float* __restrict__ Wd,
    unsigned short* __restrict__ W_T, float* __restrict__ ctrl) {
  const int k = blockIdx.x * 256 + threadIdx.x;   // 16 blocks -> 4096
#pragma unroll
  for (int c = 0; c < 21; c++)
    W_T[c * D_N + k] = f2bf(Wc[(size_t)k * 21 + c]);
#pragma unroll
  for (int c = 0; c < 21; c++)
    W_T[(21 + c) * D_N + k] = f2bf(Wd[(size_t)k * 21 + c]);
#pragma unroll
  for (int c = 42; c < 48; c++) W_T[c * D_N + k] = 0;
  if (blockIdx.x == 0 && threadIdx.x < 64) ctrl[threadIdx.x] = 0.f;  // dsum + cls_count
}

// ================= MFMA GEMM: partial[s][c][r] = x[r, ks:ks+KC) @ W[:, c] =================
// grid 512 = 64 row-blocks(64 rows) x 8 splits; 256 thr = 4 waves; wave w -> m-tile w
__global__ __launch_bounds__(256) void gemm_kernel(
    const float* __restrict__ x, const unsigned short* __restrict__ W_T,
    float* __restrict__ partial) {
  __shared__ char lds_raw[64 * 264 * 2 + NCOLP * 264 * 2];   // 33792 B + 25344 B = 59136 B
  unsigned short* xl = (unsigned short*)lds_raw;             // [row][264]
  unsigned short* wl = (unsigned short*)(lds_raw + 64 * 264 * 2); // [col][264]

  const int t = threadIdx.x;
  const int bx = blockIdx.x;
  const int r0 = (bx & 63) * RB;
  const int split = bx >> 6;
  const int l = t & 63, w = t >> 6;
  const int r16 = l & 15, q = l >> 4;

  f32x4 acc0 = {0.f, 0.f, 0.f, 0.f};
  f32x4 acc1 = {0.f, 0.f, 0.f, 0.f};
  f32x4 acc2 = {0.f, 0.f, 0.f, 0.f};
  const unsigned* wt32 = (const unsigned*)W_T;   // [48][2048] uints

  for (int kt = 0; kt < KC / KTILE; kt++) {
    const int k0 = split * KC + kt * KTILE;
    // ---- stage x tile: 64 rows x 256 k, fp32 -> bf16 ----
#pragma unroll
    for (int i = 0; i < 16; i++) {
      int f = t + i * 256;
      int row = f >> 6, kq = f & 63;
      const float4 v = *(const float4*)(x + (size_t)(r0 + row) * D_N + k0 + kq * 4);
      unsigned lo = (unsigned)f2bf(v.x) | ((unsigned)f2bf(v.y) << 16);
      unsigned hi = (unsigned)f2bf(v.z) | ((unsigned)f2bf(v.w) << 16);
      uint2 p; p.x = lo; p.y = hi;
      *(uint2*)(xl + row * 264 + kq * 4) = p;
    }
    // ---- stage W tile: 48 cols x 256 k bf16 ----
#pragma unroll
    for (int i = 0; i < 24; i++) {
      int e = t + i * 256;
      int c = e >> 7, kw = e & 127;
      unsigned v = wt32[c * (D_N / 2) + (k0 >> 1) + kw];
      *(unsigned*)(wl + c * 264 + kw * 2) = v;
    }
    __syncthreads();

    // ---- MFMA: wave w computes rows [w*16, w*16+16) x 48 cols ----
    const unsigned short* ap  = xl + (w * 16 + r16) * 264 + q * 8;
    const unsigned short* bp0 = wl + (0  + r16) * 264 + q * 8;
    const unsigned short* bp1 = wl + (16 + r16) * 264 + q * 8;
    const unsigned short* bp2 = wl + (32 + r16) * 264 + q * 8;
#pragma unroll
    for (int s = 0; s < 8; s++) {
      bf16x8 af = *(const bf16x8*)(ap + s * 32);
      acc0 = __builtin_amdgcn_mfma_f32_16x16x32_bf16(af, *(const bf16x8*)(bp0 + s * 32), acc0, 0, 0, 0);
      acc1 = __builtin_amdgcn_mfma_f32_16x16x32_bf16(af, *(const bf16x8*)(bp1 + s * 32), acc1, 0, 0, 0);
      acc2 = __builtin_amdgcn_mfma_f32_16x16x32_bf16(af, *(const bf16x8*)(bp2 + s * 32), acc2, 0, 0, 0);
    }
    __syncthreads();
  }

  // ---- transpose D-frags through LDS: cl[col][68] -> coalesced [c][r] stores ----
  float* cl = (float*)lds_raw;   // 48 x 68 floats (overlays x-tile)
  *(f32x4*)(cl + (0  + r16) * 68 + w * 16 + q * 4) = acc0;
  *(f32x4*)(cl + (16 + r16) * 68 + w * 16 + q * 4) = acc1;
  *(f32x4*)(cl + (32 + r16) * 68 + w * 16 + q * 4) = acc2;
  __syncthreads();
  float* p = partial + (size_t)split * PART_STRIDE;
#pragma unroll
  for (int i = 0; i < 3; i++) {
    int e = t + i * 256;
    int c = e >> 4, rq = e & 15;
    f32x4 v = *(const f32x4*)(cl + c * 68 + rq * 4);
    *(f32x4*)(p + (size_t)c * R_N + r0 + rq * 4) = v;
  }
}

// ====== reduce partials -> logits_T[c][r]; det cols accumulate sum-exp into dsum ======
__global__ __launch_bounds__(256) void reduce_kernel(
    const float* __restrict__ partial, const float* __restrict__ b_det,
    float* __restrict__ logits_T, float* __restrict__ dsum) {
  const int bx = blockIdx.x;          // 168 = 42 cols x 4 row-chunks
  const int c = bx >> 2;
  const int rc = bx & 3;
  const int t = threadIdx.x;
  float v[4];
#pragma unroll
  for (int j = 0; j < 4; j++) {
    int r = rc * 1024 + t + j * 256;
    float s = 0.f;
#pragma unroll
    for (int sp = 0; sp < NSPLIT; sp++)
      s += partial[(size_t)sp * PART_STRIDE + (size_t)c * R_N + r];
    v[j] = s;
    logits_T[(size_t)c * R_N + r] = s;
  }
  if (c >= 21 && c < 41) {
    const int cd = c - 21;
    const float bd = b_det[cd];
    float loc = fexp(v[0] + bd) + fexp(v[1] + bd) + fexp(v[2] + bd) + fexp(v[3] + bd);
    for (int off = 32; off; off >>= 1) loc += __shfl_down(loc, off, 64);
    __shared__ float red[4];
    if ((t & 63) == 0) red[t >> 6] = loc;
    __syncthreads();
    if (t == 0) atomicAdd(&dsum[cd], red[0] + red[1] + red[2] + red[3]);
  }
}

// ====== scores: per-row dual softmax; compact candidates > thresh (global) ======
__global__ __launch_bounds__(256) void scores_kernel(
    const float* __restrict__ logits_T, const float* __restrict__ b_cls,
    const float* __restrict__ b_det, const float* __restrict__ dsum,
    int* __restrict__ cls_count, int* __restrict__ cand_r, float* __restrict__ cand_s) {
  const int r = blockIdx.x * 256 + threadIdx.x;   // 16 blocks -> 4096
  float l[21];
  float m = -1e30f;
#pragma unroll
  for (int c = 0; c < 21; c++) {
    l[c] = logits_T[(size_t)c * R_N + r] + b_cls[c];
    m = fmaxf(m, l[c]);
  }
  float s = 0.f;
#pragma unroll
  for (int c = 0; c < 21; c++) { l[c] = fexp(l[c] - m); s += l[c]; }
  const float inv = 1.f / s;
  for (int c = 0; c < 20; c++) {
    float ld = logits_T[(size_t)(21 + c) * R_N + r] + b_det[c];
    float sc = l[c] * inv * fexp(ld) / dsum[c];
    if (sc > SCORE_TH) {
      int p = atomicAdd(&cls_count[c], 1);
      if (p < 32) { cand_r[c * 32 + p] = r; cand_s[c * 32 + p] = sc; }
    }
  }
}

// =================== tail: per-class NMS -> top-100 (1 block) ===================
__device__ __forceinline__ void load_clip_box(const float* boxes, int r, float* b) {
  b[0] = fminf(fmaxf(boxes[r * 4 + 0], 0.f), IMG_W_F);
  b[1] = fminf(fmaxf(boxes[r * 4 + 1], 0.f), IMG_H_F);
  b[2] = fminf(fmaxf(boxes[r * 4 + 2], 0.f), IMG_W_F);
  b[3] = fminf(fmaxf(boxes[r * 4 + 3], 0.f), IMG_H_F);
}

__global__ __launch_bounds__(256) void tail_kernel(
    const int* __restrict__ cls_count, const int* __restrict__ cand_r,
    const float* __restrict__ cand_s, const float* __restrict__ boxes,
    float* __restrict__ out) {
  __shared__ int   s_kc;
  __shared__ int   s_ki[512];
  __shared__ float s_ks[512];
  __shared__ float sval[TOPK_N];
  __shared__ int   sidx[TOPK_N];
  const int t = threadIdx.x;
  if (t == 0) s_kc = 0;
  if (t < TOPK_N) { sval[t] = 0.f; sidx[t] = 0; }
  __syncthreads();

  // ---- per-class greedy NMS (threads 0..19) ----
  if (t < 20) {
    const int c = t;
    int n = cls_count[c]; if (n > 32) n = 32;
    float s[32]; int rr[32];
    for (int i = 0; i < n; i++) { s[i] = cand_s[c * 32 + i]; rr[i] = cand_r[c * 32 + i]; }
    for (int i = 1; i < n; i++) {            // score desc, tie -> row asc
      float si = s[i]; int ri = rr[i];
      int j = i - 1;
      while (j >= 0 && (s[j] < si || (s[j] == si && rr[j] > ri))) {
        s[j + 1] = s[j]; rr[j + 1] = rr[j]; j--;
      }
      s[j + 1] = si; rr[j + 1] = ri;
    }
    unsigned supp = 0;
    for (int i = 0; i < n; i++) {
      if (supp & (1u << i)) continue;
      int g = atomicAdd(&s_kc, 1);
      if (g < 512) { s_ki[g] = rr[i] * C_N + c; s_ks[g] = s[i]; }
      float bi[4]; load_clip_box(boxes, rr[i], bi);
      float ai = (bi[2] - bi[0]) * (bi[3] - bi[1]);
      for (int j = i + 1; j < n; j++) {
        if (supp & (1u << j)) continue;
        float bj[4]; load_clip_box(boxes, rr[j], bj);
        float aj = (bj[2] - bj[0]) * (bj[3] - bj[1]);
        float lx = fmaxf(bi[0], bj[0]), ly = fmaxf(bi[1], bj[1]);
        float rx = fminf(bi[2], bj[2]), ry = fminf(bi[3], bj[3]);
        float wdt = fmaxf(rx - lx, 0.f), hgt = fmaxf(ry - ly, 0.f);
        float inter = wdt * hgt;
        float iou = inter / (ai + aj - inter + 1e-9f);
        if (iou > NMS_TH) supp |= (1u << j);
      }
    }
  }
  __syncthreads();

  // ---- top-100 with jax.lax.top_k tie rules ----
  int m = s_kc; if (m > 512) m = 512;
  for (int i = t; i < m; i += 256) {
    float si = s_ks[i]; int xi = s_ki[i];
    int rank = 0;
    for (int j = 0; j < m; j++) {
      float sj = s_ks[j]; int xj = s_ki[j];
      if (sj > si || (sj == si && xj < xi)) rank++;
    }
    if (rank < TOPK_N) { sval[rank] = si; sidx[rank] = xi; }
  }
  __syncthreads();
  if (t == 0) {
    int f = m < TOPK_N ? m : TOPK_N;
    int cur = 0;
    for (int slot = f; slot < TOPK_N; slot++) {
      for (;;) {
        bool member = false;
        for (int j = 0; j < m; j++)
          if (s_ki[j] == cur) { member = true; break; }
        if (!member) break;
        cur++;
      }
      sval[slot] = 0.f;
      sidx[slot] = cur;
      cur++;
    }
  }
  __syncthreads();
  if (t < TOPK_N) {
    int idx = sidx[t];
    int prop = idx / C_N;
    int cls = idx - prop * C_N;
    float b[4]; load_clip_box(boxes, prop, b);
    out[t] = sval[t];
    out[TOPK_N + t * 4 + 0] = b[0];
    out[TOPK_N + t * 4 + 1] = b[1];
    out[TOPK_N + t * 4 + 2] = b[2];
    out[TOPK_N + t * 4 + 3] = b[3];
    out[TOPK_N * 5 + t] = (float)cls;
  }
}

extern "C" void kernel_launch(void* const* d_in, const int* in_sizes, int n_in,
                              void* d_out, int out_size, void* d_ws, size_t ws_size,
                              hipStream_t stream) {
  const float* x     = (const float*)d_in[0];
  const float* boxes = (const float*)d_in[1];
  const float* W_cls = (const float*)d_in[2];
  const float* b_cls = (const float*)d_in[3];
  const float* W_det = (const float*)d_in[4];
  const float* b_det = (const float*)d_in[5];
  float* out = (float*)d_out;

  float* ws = (float*)d_ws;
  unsigned short* W_T = (unsigned short*)ws;          // 48x4096 bf16
  float* partial   = ws + PART_OFF;
  float* logits_T  = ws + LOGT_OFF;
  float* dsum      = ws + CTRL_OFF;                   // 20 f32
  int*   cls_count = (int*)(ws + CTRL_OFF) + 20;      // 20 ints
  int*   cand_r    = (int*)(ws + CAND_R_OFF);
  float* cand_s    = ws + CAND_S_OFF;

  wT_kernel    <<<16,  256, 0, stream>>>(W_cls, W_det, W_T, dsum);
  gemm_kernel  <<<512, 256, 0, stream>>>(x, W_T, partial);
  reduce_kernel<<<168, 256, 0, stream>>>(partial, b_det, logits_T, dsum);
  scores_kernel<<<16,  256, 0, stream>>>(logits_T, b_cls, b_det, dsum,
                                         cls_count, cand_r, cand_s);
  tail_kernel  <<<1,   256, 0, stream>>>(cls_count, cand_r, cand_s, boxes, out);
}

// Round 5
// 130.995 us; speedup vs baseline: 3.3859x; 1.0684x over previous
//
#include <hip/hip_runtime.h>
#include <math.h>

#define R_N 4096
#define D_N 4096
#define C_N 20
#define IMG_W_F 1216.0f
#define IMG_H_F 800.0f
#define SCORE_TH 0.05f
#define NMS_TH 0.5f
#define TOPK_N 100

#define NSPLIT 8
#define NCOLP 48                 // 21 cls + 21 det + 6 zero pad
#define KC 512                   // K per split
#define KSTEPS (KC / 32)         // 16 mfma K-steps

// ---- workspace layout (units: 4-byte words) ----
#define WT_WORDS   (NCOLP * D_N / 2)                 // 48x4096 bf16 = 98304 words
#define PART_OFF   (WT_WORDS)
#define PART_STRIDE (NCOLP * R_N)                    // 196608 words per split
#define PART_WORDS (NSPLIT * PART_STRIDE)            // 1572864
#define LOGT_OFF   (PART_OFF + PART_WORDS)           // logits_T [42][4096]
#define LOGT_WORDS (42 * R_N)
#define CTRL_OFF   (LOGT_OFF + LOGT_WORDS)           // dsum[20] | cls_count[20] | pad -> 64 words
#define CAND_R_OFF (CTRL_OFF + 64)                   // 20*32 ints
#define CAND_S_OFF (CAND_R_OFF + 640)                // 20*32 f32

typedef short bf16x8 __attribute__((ext_vector_type(8)));
typedef float f32x4  __attribute__((ext_vector_type(4)));

__device__ __forceinline__ unsigned short f2bf(float f) {
  union { float f; unsigned u; } v; v.f = f;
  unsigned r = (v.u + 0x7FFFu + ((v.u >> 16) & 1u)) >> 16;
  return (unsigned short)r;
}
// truncating pack: result = {hi16(a), hi16(b)} — one v_perm_b32
__device__ __forceinline__ unsigned pk(float a, float b) {
  return __builtin_amdgcn_perm(__float_as_uint(a), __float_as_uint(b), 0x07060302u);
}
__device__ __forceinline__ float fexp(float x) { return __expf(x); }

// ============ W transpose + bf16 convert; also zero ctrl words ============
__global__ __launch_bounds__(256) void wT_kernel(
    const float* __restrict__ Wc, const float* __restrict__ Wd,
    unsigned short* __restrict__ W_T, float* __restrict__ ctrl) {
  const int k = blockIdx.x * 256 + threadIdx.x;   // 16 blocks -> 4096
#pragma unroll
  for (int c = 0; c < 21; c++)
    W_T[c * D_N + k] = f2bf(Wc[(size_t)k * 21 + c]);
#pragma unroll
  for (int c = 0; c < 21; c++)
    W_T[(21 + c) * D_N + k] = f2bf(Wd[(size_t)k * 21 + c]);
#pragma unroll
  for (int c = 42; c < 48; c++) W_T[c * D_N + k] = 0;
  if (blockIdx.x == 0 && threadIdx.x < 64) ctrl[threadIdx.x] = 0.f;  // dsum + cls_count
}

// ================= MFMA GEMM, barrier-free K-loop =================
// partial[s][c][r] = x[r, ks:ks+KC) @ W[:, c]
// grid 512 = 64 row-blocks(64 rows) x 8 splits; 4 waves; wave w -> rows w*16..w*16+15
// A operand: direct from global (16 rows x 128B lines per load pair), trunc-pack to bf16.
// B operand: staged once into frag-linear LDS (lane -> consecutive 16B, conflict-free).
__global__ __launch_bounds__(256) void gemm_kernel(
    const float* __restrict__ x, const unsigned short* __restrict__ W_T,
    float* __restrict__ partial) {
  __shared__ char lds_raw[KSTEPS * 3 * 64 * 16];   // 48 KB W-frags; epilogue overlays
  unsigned short* wf = (unsigned short*)lds_raw;

  const int t = threadIdx.x;
  const int bx = blockIdx.x;
  const int r0 = (bx & 63) * 64;
  const int split = bx >> 6;
  const int k0 = split * KC;
  const int l = t & 63, w = t >> 6;
  const int r16 = l & 15, q = l >> 4;

  // ---- stage W frags: 48 cols x 512 k bf16, frag-linear layout ----
  const unsigned* wt32 = (const unsigned*)W_T;     // [48][2048] uints
#pragma unroll
  for (int i = 0; i < 12; i++) {
    int e = t + i * 256;                           // 3072 = 48 cols x 64 k8-chunks
    int c = e >> 6, k8 = e & 63;
    uint4 v = *(const uint4*)(wt32 + c * (D_N / 2) + (k0 >> 1) + k8 * 4);
    int frag = ((k8 >> 2) * 3 + (c >> 4)) * 64 + (c & 15) + (k8 & 3) * 16;
    *(uint4*)(lds_raw + frag * 16) = v;
  }
  __syncthreads();

  // ---- K-loop: no barriers; loads pipeline freely ----
  const float* xrow = x + (size_t)(r0 + w * 16 + r16) * D_N + k0 + q * 8;
  f32x4 acc0 = {0.f, 0.f, 0.f, 0.f};
  f32x4 acc1 = {0.f, 0.f, 0.f, 0.f};
  f32x4 acc2 = {0.f, 0.f, 0.f, 0.f};

  float4 p0 = *(const float4*)(xrow);
  float4 p1 = *(const float4*)(xrow + 4);
#pragma unroll
  for (int s = 0; s < KSTEPS; s++) {
    float4 n0, n1;
    if (s + 1 < KSTEPS) {
      n0 = *(const float4*)(xrow + (s + 1) * 32);
      n1 = *(const float4*)(xrow + (s + 1) * 32 + 4);
    }
    union { bf16x8 v; unsigned u[4]; } af;
    af.u[0] = pk(p0.y, p0.x);
    af.u[1] = pk(p0.w, p0.z);
    af.u[2] = pk(p1.y, p1.x);
    af.u[3] = pk(p1.w, p1.z);
    bf16x8 b0 = *(const bf16x8*)(wf + (size_t)((s * 3 + 0) * 64 + l) * 8);
    bf16x8 b1 = *(const bf16x8*)(wf + (size_t)((s * 3 + 1) * 64 + l) * 8);
    bf16x8 b2 = *(const bf16x8*)(wf + (size_t)((s * 3 + 2) * 64 + l) * 8);
    acc0 = __builtin_amdgcn_mfma_f32_16x16x32_bf16(af.v, b0, acc0, 0, 0, 0);
    acc1 = __builtin_amdgcn_mfma_f32_16x16x32_bf16(af.v, b1, acc1, 0, 0, 0);
    acc2 = __builtin_amdgcn_mfma_f32_16x16x32_bf16(af.v, b2, acc2, 0, 0, 0);
    p0 = n0; p1 = n1;
  }

  // ---- transpose D-frags through LDS -> coalesced [c][r] stores ----
  __syncthreads();                                 // done reading wf; overlay as cl
  float* cl = (float*)lds_raw;                     // 48 x 68 floats
  // lane holds D[row = w*16 + q*4 + reg][col = ct*16 + r16]
  *(f32x4*)(cl + (0  + r16) * 68 + w * 16 + q * 4) = acc0;
  *(f32x4*)(cl + (16 + r16) * 68 + w * 16 + q * 4) = acc1;
  *(f32x4*)(cl + (32 + r16) * 68 + w * 16 + q * 4) = acc2;
  __syncthreads();
  float* p = partial + (size_t)split * PART_STRIDE;
#pragma unroll
  for (int i = 0; i < 3; i++) {
    int e = t + i * 256;
    int c = e >> 4, rq = e & 15;
    f32x4 v = *(const f32x4*)(cl + c * 68 + rq * 4);
    *(f32x4*)(p + (size_t)c * R_N + r0 + rq * 4) = v;
  }
}

// ====== reduce partials -> logits_T[c][r]; det cols accumulate sum-exp into dsum ======
__global__ __launch_bounds__(256) void reduce_kernel(
    const float* __restrict__ partial, const float* __restrict__ b_det,
    float* __restrict__ logits_T, float* __restrict__ dsum) {
  const int bx = blockIdx.x;          // 168 = 42 cols x 4 row-chunks
  const int c = bx >> 2;
  const int rc = bx & 3;
  const int t = threadIdx.x;
  float v[4];
#pragma unroll
  for (int j = 0; j < 4; j++) {
    int r = rc * 1024 + t + j * 256;
    float s = 0.f;
#pragma unroll
    for (int sp = 0; sp < NSPLIT; sp++)
      s += partial[(size_t)sp * PART_STRIDE + (size_t)c * R_N + r];
    v[j] = s;
    logits_T[(size_t)c * R_N + r] = s;
  }
  if (c >= 21 && c < 41) {
    const int cd = c - 21;
    const float bd = b_det[cd];
    float loc = fexp(v[0] + bd) + fexp(v[1] + bd) + fexp(v[2] + bd) + fexp(v[3] + bd);
    for (int off = 32; off; off >>= 1) loc += __shfl_down(loc, off, 64);
    __shared__ float red[4];
    if ((t & 63) == 0) red[t >> 6] = loc;
    __syncthreads();
    if (t == 0) atomicAdd(&dsum[cd], red[0] + red[1] + red[2] + red[3]);
  }
}

// ====== scores: per-row dual softmax; compact candidates > thresh (global) ======
__global__ __launch_bounds__(256) void scores_kernel(
    const float* __restrict__ logits_T, const float* __restrict__ b_cls,
    const float* __restrict__ b_det, const float* __restrict__ dsum,
    int* __restrict__ cls_count, int* __restrict__ cand_r, float* __restrict__ cand_s) {
  const int r = blockIdx.x * 256 + threadIdx.x;   // 16 blocks -> 4096
  float l[21];
  float m = -1e30f;
#pragma unroll
  for (int c = 0; c < 21; c++) {
    l[c] = logits_T[(size_t)c * R_N + r] + b_cls[c];
    m = fmaxf(m, l[c]);
  }
  float s = 0.f;
#pragma unroll
  for (int c = 0; c < 21; c++) { l[c] = fexp(l[c] - m); s += l[c]; }
  const float inv = 1.f / s;
  for (int c = 0; c < 20; c++) {
    float ld = logits_T[(size_t)(21 + c) * R_N + r] + b_det[c];
    float sc = l[c] * inv * fexp(ld) / dsum[c];
    if (sc > SCORE_TH) {
      int p = atomicAdd(&cls_count[c], 1);
      if (p < 32) { cand_r[c * 32 + p] = r; cand_s[c * 32 + p] = sc; }
    }
  }
}

// =================== tail: per-class NMS -> top-100 (1 block) ===================
__device__ __forceinline__ void load_clip_box(const float* boxes, int r, float* b) {
  b[0] = fminf(fmaxf(boxes[r * 4 + 0], 0.f), IMG_W_F);
  b[1] = fminf(fmaxf(boxes[r * 4 + 1], 0.f), IMG_H_F);
  b[2] = fminf(fmaxf(boxes[r * 4 + 2], 0.f), IMG_W_F);
  b[3] = fminf(fmaxf(boxes[r * 4 + 3], 0.f), IMG_H_F);
}

__global__ __launch_bounds__(256) void tail_kernel(
    const int* __restrict__ cls_count, const int* __restrict__ cand_r,
    const float* __restrict__ cand_s, const float* __restrict__ boxes,
    float* __restrict__ out) {
  __shared__ int   s_kc;
  __shared__ int   s_ki[512];
  __shared__ float s_ks[512];
  __shared__ float sval[TOPK_N];
  __shared__ int   sidx[TOPK_N];
  const int t = threadIdx.x;
  if (t == 0) s_kc = 0;
  if (t < TOPK_N) { sval[t] = 0.f; sidx[t] = 0; }
  __syncthreads();

  // ---- per-class greedy NMS (threads 0..19) ----
  if (t < 20) {
    const int c = t;
    int n = cls_count[c]; if (n > 32) n = 32;
    float s[32]; int rr[32];
    for (int i = 0; i < n; i++) { s[i] = cand_s[c * 32 + i]; rr[i] = cand_r[c * 32 + i]; }
    for (int i = 1; i < n; i++) {            // score desc, tie -> row asc
      float si = s[i]; int ri = rr[i];
      int j = i - 1;
      while (j >= 0 && (s[j] < si || (s[j] == si && rr[j] > ri))) {
        s[j + 1] = s[j]; rr[j + 1] = rr[j]; j--;
      }
      s[j + 1] = si; rr[j + 1] = ri;
    }
    unsigned supp = 0;
    for (int i = 0; i < n; i++) {
      if (supp & (1u << i)) continue;
      int g = atomicAdd(&s_kc, 1);
      if (g < 512) { s_ki[g] = rr[i] * C_N + c; s_ks[g] = s[i]; }
      float bi[4]; load_clip_box(boxes, rr[i], bi);
      float ai = (bi[2] - bi[0]) * (bi[3] - bi[1]);
      for (int j = i + 1; j < n; j++) {
        if (supp & (1u << j)) continue;
        float bj[4]; load_clip_box(boxes, rr[j], bj);
        float aj = (bj[2] - bj[0]) * (bj[3] - bj[1]);
        float lx = fmaxf(bi[0], bj[0]), ly = fmaxf(bi[1], bj[1]);
        float rx = fminf(bi[2], bj[2]), ry = fminf(bi[3], bj[3]);
        float wdt = fmaxf(rx - lx, 0.f), hgt = fmaxf(ry - ly, 0.f);
        float inter = wdt * hgt;
        float iou = inter / (ai + aj - inter + 1e-9f);
        if (iou > NMS_TH) supp |= (1u << j);
      }
    }
  }
  __syncthreads();

  // ---- top-100 with jax.lax.top_k tie rules ----
  int m = s_kc; if (m > 512) m = 512;
  for (int i = t; i < m; i += 256) {
    float si = s_ks[i]; int xi = s_ki[i];
    int rank = 0;
    for (int j = 0; j < m; j++) {
      float sj = s_ks[j]; int xj = s_ki[j];
      if (sj > si || (sj == si && xj < xi)) rank++;
    }
    if (rank < TOPK_N) { sval[rank] = si; sidx[rank] = xi; }
  }
  __syncthreads();
  if (t == 0) {
    int f = m < TOPK_N ? m : TOPK_N;
    int cur = 0;
    for (int slot = f; slot < TOPK_N; slot++) {
      for (;;) {
        bool member = false;
        for (int j = 0; j < m; j++)
          if (s_ki[j] == cur) { member = true; break; }
        if (!member) break;
        cur++;
      }
      sval[slot] = 0.f;
      sidx[slot] = cur;
      cur++;
    }
  }
  __syncthreads();
  if (t < TOPK_N) {
    int idx = sidx[t];
    int prop = idx / C_N;
    int cls = idx - prop * C_N;
    float b[4]; load_clip_box(boxes, prop, b);
    out[t] = sval[t];
    out[TOPK_N + t * 4 + 0] = b[0];
    out[TOPK_N + t * 4 + 1] = b[1];
    out[TOPK_N + t * 4 + 2] = b[2];
    out[TOPK_N + t * 4 + 3] = b[3];
    out[TOPK_N * 5 + t] = (float)cls;
  }
}

extern "C" void kernel_launch(void* const* d_in, const int* in_sizes, int n_in,
                              void* d_out, int out_size, void* d_ws, size_t ws_size,
                              hipStream_t stream) {
  const float* x     = (const float*)d_in[0];
  const float* boxes = (const float*)d_in[1];
  const float* W_cls = (const float*)d_in[2];
  const float* b_cls = (const float*)d_in[3];
  const float* W_det = (const float*)d_in[4];
  const float* b_det = (const float*)d_in[5];
  float* out = (float*)d_out;

  float* ws = (float*)d_ws;
  unsigned short* W_T = (unsigned short*)ws;          // 48x4096 bf16
  float* partial   = ws + PART_OFF;
  float* logits_T  = ws + LOGT_OFF;
  float* dsum      = ws + CTRL_OFF;                   // 20 f32
  int*   cls_count = (int*)(ws + CTRL_OFF) + 20;      // 20 ints
  int*   cand_r    = (int*)(ws + CAND_R_OFF);
  float* cand_s    = ws + CAND_S_OFF;

  wT_kernel    <<<16,  256, 0, stream>>>(W_cls, W_det, W_T, dsum);
  gemm_kernel  <<<512, 256, 0, stream>>>(x, W_T, partial);
  reduce_kernel<<<168, 256, 0, stream>>>(partial, b_det, logits_T, dsum);
  scores_kernel<<<16,  256, 0, stream>>>(logits_T, b_cls, b_det, dsum,
                                         cls_count, cand_r, cand_s);
  tail_kernel  <<<1,   256, 0, stream>>>(cls_count, cand_r, cand_s, boxes, out);
}

// Round 6
// 125.647 us; speedup vs baseline: 3.5301x; 1.0426x over previous
//
#include <hip/hip_runtime.h>
#include <math.h>

#define R_N 4096
#define D_N 4096
#define C_N 20
#define IMG_W_F 1216.0f
#define IMG_H_F 800.0f
#define SCORE_TH 0.05f
#define NMS_TH 0.5f
#define TOPK_N 100

// ---- workspace layout (units: 4-byte words) ----
// W_T frag-linear bf16: 128 gs x 3 ct x 64 lanes x 16B = 393216 B
#define WT_WORDS   (48 * D_N / 2)                    // 98304 words
#define ASC_OFF    (WT_WORDS)                        // Ascore[4096][20] f32
#define ASC_WORDS  (R_N * C_N)                       // 81920
#define CTRL_OFF   (ASC_OFF + ASC_WORDS)             // dsum f32[20] | cls_count i32[20] | done i32 | pad -> 64
#define CAND_R_OFF (CTRL_OFF + 64)                   // 20*32 ints
#define CAND_S_OFF (CAND_R_OFF + 640)                // 20*32 f32

typedef short bf16x8 __attribute__((ext_vector_type(8)));
typedef float f32x4  __attribute__((ext_vector_type(4)));

// truncating bf16 pack: result = {hi16(a) , hi16(b)} -> lo short = bf16(b), hi = bf16(a)
__device__ __forceinline__ unsigned pk(float a, float b) {
  return __builtin_amdgcn_perm(__float_as_uint(a), __float_as_uint(b), 0x07060302u);
}
__device__ __forceinline__ float fexp(float x) { return __expf(x); }

// ============ W -> frag-linear bf16 W_T; zero control words ============
// lane-frag e (0..24575): l=e&63, ct=(e>>6)%3, gs=(e>>6)/3
// holds B[k = gs*32 + (l>>4)*8 + j][col = ct*16 + (l&15)], j=0..7 -> one uint4
__global__ __launch_bounds__(256) void wT_kernel(
    const float* __restrict__ Wc, const float* __restrict__ Wd,
    uint4* __restrict__ Wfrag, float* __restrict__ ctrl) {
  const int e = blockIdx.x * 256 + threadIdx.x;     // 96 blocks -> 24576
  const int l = e & 63;
  const int rest = e >> 6;
  const int ct = rest % 3;
  const int gs = rest / 3;
  const int c = ct * 16 + (l & 15);
  const int k0 = gs * 32 + (l >> 4) * 8;
  float w[8];
  if (c < 21) {
#pragma unroll
    for (int j = 0; j < 8; j++) w[j] = Wc[(size_t)(k0 + j) * 21 + c];
  } else if (c < 42) {
#pragma unroll
    for (int j = 0; j < 8; j++) w[j] = Wd[(size_t)(k0 + j) * 21 + (c - 21)];
  } else {
#pragma unroll
    for (int j = 0; j < 8; j++) w[j] = 0.f;
  }
  uint4 v;
  v.x = pk(w[1], w[0]); v.y = pk(w[3], w[2]);
  v.z = pk(w[5], w[4]); v.w = pk(w[7], w[6]);
  Wfrag[(gs * 3 + ct) * 64 + l] = v;
  if (e < 64) ctrl[e] = 0.f;                        // dsum + cls_count + done
}

// ============ full-K MFMA GEMM + fused dual-softmax partials ============
// 256 blocks x 512 thr (8 waves). Block = rows r0..r0+15, wave w = K [w*512,(w+1)*512).
// K-loop: barrier-free; A direct from global (trunc->bf16), B direct from global (frag-linear).
// Epilogue: LDS cross-wave K-reduce -> cls softmax * exp(det) -> Ascore; atomicAdd dsum.
__global__ __launch_bounds__(512) void gemm_kernel(
    const float* __restrict__ x, const uint4* __restrict__ Wfrag,
    float* __restrict__ Ascore, const float* __restrict__ b_cls,
    const float* __restrict__ b_det, float* __restrict__ dsum) {
  __shared__ float red[8 * 48 * 16];                // 24 KB
  const int t = threadIdx.x;
  const int w = t >> 6, l = t & 63;
  const int r16 = l & 15, q = l >> 4;
  const int r0 = blockIdx.x * 16;

  const float* xrow = x + (size_t)(r0 + r16) * D_N + w * 512 + q * 8;
  f32x4 acc0 = {0.f, 0.f, 0.f, 0.f};
  f32x4 acc1 = {0.f, 0.f, 0.f, 0.f};
  f32x4 acc2 = {0.f, 0.f, 0.f, 0.f};

#pragma unroll 4
  for (int s = 0; s < 16; s++) {
    float4 a0 = *(const float4*)(xrow + s * 32);
    float4 a1 = *(const float4*)(xrow + s * 32 + 4);
    const int gs = w * 16 + s;
    union { uint4 u; bf16x8 v; } b0, b1, b2;
    b0.u = Wfrag[(gs * 3 + 0) * 64 + l];
    b1.u = Wfrag[(gs * 3 + 1) * 64 + l];
    b2.u = Wfrag[(gs * 3 + 2) * 64 + l];
    union { bf16x8 v; unsigned u[4]; } af;
    af.u[0] = pk(a0.y, a0.x);
    af.u[1] = pk(a0.w, a0.z);
    af.u[2] = pk(a1.y, a1.x);
    af.u[3] = pk(a1.w, a1.z);
    acc0 = __builtin_amdgcn_mfma_f32_16x16x32_bf16(af.v, b0.v, acc0, 0, 0, 0);
    acc1 = __builtin_amdgcn_mfma_f32_16x16x32_bf16(af.v, b1.v, acc1, 0, 0, 0);
    acc2 = __builtin_amdgcn_mfma_f32_16x16x32_bf16(af.v, b2.v, acc2, 0, 0, 0);
  }

  // ---- cross-wave K-reduction in LDS ----
  // lane l reg j holds D[row = q*4+j][col = ct*16 + r16] for wave w
  *(f32x4*)(&red[(w * 48 + 0  + r16) * 16 + q * 4]) = acc0;
  *(f32x4*)(&red[(w * 48 + 16 + r16) * 16 + q * 4]) = acc1;
  *(f32x4*)(&red[(w * 48 + 32 + r16) * 16 + q * 4]) = acc2;
  __syncthreads();
  for (int o = t; o < 768; o += 512) {              // o = c*16 + row
    float v = 0.f;
#pragma unroll
    for (int w2 = 0; w2 < 8; w2++) v += red[w2 * 768 + o];
    red[o] = v;                                     // safe: each thread reads red[0*768+o] only for its own o
  }
  __syncthreads();

  // ---- fused scores numerator: Ascore[r][c] = softmax_cls(r)[c] * exp(det+bd) ----
  if (t < 16) {
    const int r = t;
    float lg[21], m = -1e30f;
#pragma unroll
    for (int c = 0; c < 21; c++) {
      lg[c] = red[c * 16 + r] + b_cls[c];
      m = fmaxf(m, lg[c]);
    }
    float s = 0.f;
#pragma unroll
    for (int c = 0; c < 21; c++) { lg[c] = fexp(lg[c] - m); s += lg[c]; }
    const float inv = 1.f / s;
#pragma unroll
    for (int c = 0; c < 20; c++) {
      float e = fexp(red[(21 + c) * 16 + r] + b_det[c]);
      Ascore[(size_t)(r0 + r) * C_N + c] = lg[c] * inv * e;
    }
  } else if (t < 36) {
    const int cd = t - 16;
    const float bd = b_det[cd];
    float s = 0.f;
#pragma unroll
    for (int r = 0; r < 16; r++) s += fexp(red[(21 + cd) * 16 + r] + bd);
    atomicAdd(&dsum[cd], s);
  }
}

// ============ finish: scores -> compact; last block: NMS -> top-100 ============
__device__ __forceinline__ void load_clip_box(const float* boxes, int r, float* b) {
  b[0] = fminf(fmaxf(boxes[r * 4 + 0], 0.f), IMG_W_F);
  b[1] = fminf(fmaxf(boxes[r * 4 + 1], 0.f), IMG_H_F);
  b[2] = fminf(fmaxf(boxes[r * 4 + 2], 0.f), IMG_W_F);
  b[3] = fminf(fmaxf(boxes[r * 4 + 3], 0.f), IMG_H_F);
}

__global__ __launch_bounds__(256) void finish_kernel(
    const float* __restrict__ Ascore, const float* __restrict__ dsum,
    int* __restrict__ cls_count, int* __restrict__ done,
    int* __restrict__ cand_r, float* __restrict__ cand_s,
    const float* __restrict__ boxes, float* __restrict__ out) {
  __shared__ float sd[20];
  __shared__ bool s_last;
  const int t = threadIdx.x;
  if (t < 20) sd[t] = dsum[t];
  __syncthreads();

  // ---- phase 1: score + candidate compaction (all 16 blocks) ----
  const int r = blockIdx.x * 256 + t;
  for (int c = 0; c < 20; c++) {
    float sc = Ascore[(size_t)r * C_N + c] / sd[c];
    if (sc > SCORE_TH) {
      int p = atomicAdd(&cls_count[c], 1);
      if (p < 32) { cand_r[c * 32 + p] = r; cand_s[c * 32 + p] = sc; }
    }
  }
  __threadfence();                                  // release candidate writes (agent scope)
  __syncthreads();
  if (t == 0) {
    int old = atomicAdd(done, 1);
    s_last = (old == 15);
  }
  __syncthreads();
  if (!s_last) return;
  __threadfence();                                  // acquire side

  // ---- phase 2 (last block only): per-class NMS -> top-100 ----
  __shared__ int   s_kc;
  __shared__ int   s_ki[512];
  __shared__ float s_ks[512];
  __shared__ float sval[TOPK_N];
  __shared__ int   sidx[TOPK_N];
  if (t == 0) s_kc = 0;
  if (t < TOPK_N) { sval[t] = 0.f; sidx[t] = 0; }
  __syncthreads();

  if (t < 20) {
    const int c = t;
    int n = cls_count[c]; if (n > 32) n = 32;
    float s[32]; int rr[32];
    for (int i = 0; i < n; i++) { s[i] = cand_s[c * 32 + i]; rr[i] = cand_r[c * 32 + i]; }
    for (int i = 1; i < n; i++) {                   // score desc, tie -> row asc
      float si = s[i]; int ri = rr[i];
      int j = i - 1;
      while (j >= 0 && (s[j] < si || (s[j] == si && rr[j] > ri))) {
        s[j + 1] = s[j]; rr[j + 1] = rr[j]; j--;
      }
      s[j + 1] = si; rr[j + 1] = ri;
    }
    unsigned supp = 0;
    for (int i = 0; i < n; i++) {
      if (supp & (1u << i)) continue;
      int g = atomicAdd(&s_kc, 1);
      if (g < 512) { s_ki[g] = rr[i] * C_N + c; s_ks[g] = s[i]; }
      float bi[4]; load_clip_box(boxes, rr[i], bi);
      float ai = (bi[2] - bi[0]) * (bi[3] - bi[1]);
      for (int j = i + 1; j < n; j++) {
        if (supp & (1u << j)) continue;
        float bj[4]; load_clip_box(boxes, rr[j], bj);
        float aj = (bj[2] - bj[0]) * (bj[3] - bj[1]);
        float lx = fmaxf(bi[0], bj[0]), ly = fmaxf(bi[1], bj[1]);
        float rx = fminf(bi[2], bj[2]), ry = fminf(bi[3], bj[3]);
        float wdt = fmaxf(rx - lx, 0.f), hgt = fmaxf(ry - ly, 0.f);
        float inter = wdt * hgt;
        float iou = inter / (ai + aj - inter + 1e-9f);
        if (iou > NMS_TH) supp |= (1u << j);
      }
    }
  }
  __syncthreads();

  int m = s_kc; if (m > 512) m = 512;
  for (int i = t; i < m; i += 256) {
    float si = s_ks[i]; int xi = s_ki[i];
    int rank = 0;
    for (int j = 0; j < m; j++) {
      float sj = s_ks[j]; int xj = s_ki[j];
      if (sj > si || (sj == si && xj < xi)) rank++;
    }
    if (rank < TOPK_N) { sval[rank] = si; sidx[rank] = xi; }
  }
  __syncthreads();
  if (t == 0) {
    int f = m < TOPK_N ? m : TOPK_N;
    int cur = 0;
    for (int slot = f; slot < TOPK_N; slot++) {
      for (;;) {
        bool member = false;
        for (int j = 0; j < m; j++)
          if (s_ki[j] == cur) { member = true; break; }
        if (!member) break;
        cur++;
      }
      sval[slot] = 0.f;
      sidx[slot] = cur;
      cur++;
    }
  }
  __syncthreads();
  if (t < TOPK_N) {
    int idx = sidx[t];
    int prop = idx / C_N;
    int cls = idx - prop * C_N;
    float b[4]; load_clip_box(boxes, prop, b);
    out[t] = sval[t];
    out[TOPK_N + t * 4 + 0] = b[0];
    out[TOPK_N + t * 4 + 1] = b[1];
    out[TOPK_N + t * 4 + 2] = b[2];
    out[TOPK_N + t * 4 + 3] = b[3];
    out[TOPK_N * 5 + t] = (float)cls;
  }
}

extern "C" void kernel_launch(void* const* d_in, const int* in_sizes, int n_in,
                              void* d_out, int out_size, void* d_ws, size_t ws_size,
                              hipStream_t stream) {
  const float* x     = (const float*)d_in[0];
  const float* boxes = (const float*)d_in[1];
  const float* W_cls = (const float*)d_in[2];
  const float* b_cls = (const float*)d_in[3];
  const float* W_det = (const float*)d_in[4];
  const float* b_det = (const float*)d_in[5];
  float* out = (float*)d_out;

  float* ws = (float*)d_ws;
  uint4* Wfrag     = (uint4*)ws;                     // frag-linear bf16 W
  float* Ascore    = ws + ASC_OFF;
  float* dsum      = ws + CTRL_OFF;                  // 20 f32
  int*   cls_count = (int*)(ws + CTRL_OFF) + 20;     // 20 i32
  int*   done      = (int*)(ws + CTRL_OFF) + 40;     // 1 i32
  int*   cand_r    = (int*)(ws + CAND_R_OFF);
  float* cand_s    = ws + CAND_S_OFF;

  wT_kernel    <<<96,  256, 0, stream>>>(W_cls, W_det, Wfrag, dsum);
  gemm_kernel  <<<256, 512, 0, stream>>>(x, Wfrag, Ascore, b_cls, b_det, dsum);
  finish_kernel<<<16,  256, 0, stream>>>(Ascore, dsum, cls_count, done,
                                         cand_r, cand_s, boxes, out);
}

// Round 7
// 124.022 us; speedup vs baseline: 3.5763x; 1.0131x over previous
//
#include <hip/hip_runtime.h>
#include <math.h>

#define R_N 4096
#define D_N 4096
#define C_N 20
#define IMG_W_F 1216.0f
#define IMG_H_F 800.0f
#define SCORE_TH 0.05f
#define NMS_TH 0.5f
#define TOPK_N 100

// ---- workspace layout (units: 4-byte words) ----
// Wfrag: 128 gs x 2 ct x 64 lanes x 16 B = 256 KB (det cols 0..20, 21..31 zero)
#define WF_WORDS   (128 * 2 * 64 * 4)                // 65536
#define DET_OFF    (WF_WORDS)                        // detlog[4096][24] f32 (cols 0..20 valid)
#define DET_WORDS  (R_N * 24)
#define CTRL_OFF   (DET_OFF + DET_WORDS)             // dsum f32[24] | nc i32[20] | done i32 -> 64 words
#define CAND_R_OFF (CTRL_OFF + 64)                   // 20*32 ints
#define CAND_D_OFF (CAND_R_OFF + 640)                // 20*32 f32 (det_sm)
#define CAND_S_OFF (CAND_D_OFF + 640)                // 20*32 f32 (final score)

typedef short bf16x8 __attribute__((ext_vector_type(8)));
typedef float f32x4  __attribute__((ext_vector_type(4)));

// truncating bf16 pack: {hi16(a), hi16(b)} -> lo short = bf16(b), hi short = bf16(a)
__device__ __forceinline__ unsigned pk(float a, float b) {
  return __builtin_amdgcn_perm(__float_as_uint(a), __float_as_uint(b), 0x07060302u);
}
__device__ __forceinline__ float fexp(float x) { return __expf(x); }

// ============ pack W_det -> frag-linear bf16; zero control words ============
// entry e: l=e&63, ct=(e>>6)&1, gs=e>>7
// holds B[k = gs*32 + (l>>4)*8 + j][col = ct*16 + (l&15)], j=0..7
__global__ __launch_bounds__(256) void wT_kernel(
    const float* __restrict__ Wd, uint4* __restrict__ Wfrag,
    float* __restrict__ ctrl) {
  const int e = blockIdx.x * 256 + threadIdx.x;     // 64 blocks -> 16384
  const int l = e & 63;
  const int ct = (e >> 6) & 1;
  const int gs = e >> 7;
  const int c = ct * 16 + (l & 15);
  const int k0 = gs * 32 + (l >> 4) * 8;
  float w[8];
  if (c < 21) {
#pragma unroll
    for (int j = 0; j < 8; j++) w[j] = Wd[(size_t)(k0 + j) * 21 + c];
  } else {
#pragma unroll
    for (int j = 0; j < 8; j++) w[j] = 0.f;
  }
  uint4 v;
  v.x = pk(w[1], w[0]); v.y = pk(w[3], w[2]);
  v.z = pk(w[5], w[4]); v.w = pk(w[7], w[6]);
  Wfrag[(gs * 2 + ct) * 64 + l] = v;
  if (e < 64) ctrl[e] = 0.f;                        // dsum + nc + done
}

// ============ det GEMM: detlog[r][c] = x[r,:] @ Wd[:,c], full K in one block ============
// 256 blocks x 1024 thr (16 waves, 4 waves/SIMD). Block = 16 rows; wave w: K [w*256,(w+1)*256).
// Barrier-free K-loop: A direct from global (trunc->bf16), B from L2 (frag-linear, 256 KB).
// Epilogue: in-block 16-way LDS reduce -> detlog + per-class exp-sum atomics (bias cancels).
__global__ __launch_bounds__(1024) void detgemm_kernel(
    const float* __restrict__ x, const uint4* __restrict__ Wfrag,
    float* __restrict__ detlog, float* __restrict__ dsum) {
  __shared__ float red[16 * 512];                   // 32 KB
  const int t = threadIdx.x;
  const int w = t >> 6, l = t & 63;
  const int r16 = l & 15, q = l >> 4;
  const int r0 = blockIdx.x * 16;

  const float* xrow = x + (size_t)(r0 + r16) * D_N + w * 256 + q * 8;
  f32x4 acc0 = {0.f, 0.f, 0.f, 0.f};
  f32x4 acc1 = {0.f, 0.f, 0.f, 0.f};

#pragma unroll
  for (int s = 0; s < 8; s++) {
    float4 a0 = *(const float4*)(xrow + s * 32);
    float4 a1 = *(const float4*)(xrow + s * 32 + 4);
    const int gs = w * 8 + s;
    union { uint4 u; bf16x8 v; } b0, b1;
    b0.u = Wfrag[(gs * 2 + 0) * 64 + l];
    b1.u = Wfrag[(gs * 2 + 1) * 64 + l];
    union { bf16x8 v; unsigned u[4]; } af;
    af.u[0] = pk(a0.y, a0.x);
    af.u[1] = pk(a0.w, a0.z);
    af.u[2] = pk(a1.y, a1.x);
    af.u[3] = pk(a1.w, a1.z);
    acc0 = __builtin_amdgcn_mfma_f32_16x16x32_bf16(af.v, b0.v, acc0, 0, 0, 0);
    acc1 = __builtin_amdgcn_mfma_f32_16x16x32_bf16(af.v, b1.v, acc1, 0, 0, 0);
  }

  // lane l, reg j holds D[row = q*4+j][col = ct*16 + r16]; red layout [w][c][r]
  *(f32x4*)(&red[w * 512 + (0  + r16) * 16 + q * 4]) = acc0;
  *(f32x4*)(&red[w * 512 + (16 + r16) * 16 + q * 4]) = acc1;
  __syncthreads();
  if (t < 512) {                                    // o = c*16 + r
    float v = 0.f;
#pragma unroll
    for (int w2 = 0; w2 < 16; w2++) v += red[w2 * 512 + t];
    red[t] = v;                                     // each loc read only by its own thread
  }
  __syncthreads();
  if (t < 21) {                                     // class c = t
    float s = 0.f;
#pragma unroll
    for (int r = 0; r < 16; r++) {
      float v = red[t * 16 + r];
      detlog[(size_t)(r0 + r) * 24 + t] = v;
      s += fexp(v);
    }
    atomicAdd(&dsum[t], s);
  }
}

// ============ finish: det-candidates; last block: cls-on-demand -> NMS -> top-100 ============
__device__ __forceinline__ void load_clip_box(const float* boxes, int r, float* b) {
  b[0] = fminf(fmaxf(boxes[r * 4 + 0], 0.f), IMG_W_F);
  b[1] = fminf(fmaxf(boxes[r * 4 + 1], 0.f), IMG_H_F);
  b[2] = fminf(fmaxf(boxes[r * 4 + 2], 0.f), IMG_W_F);
  b[3] = fminf(fmaxf(boxes[r * 4 + 3], 0.f), IMG_H_F);
}

__global__ __launch_bounds__(256) void finish_kernel(
    const float* __restrict__ x, const float* __restrict__ Wc,
    const float* __restrict__ b_cls, const float* __restrict__ detlog,
    const float* __restrict__ dsum, int* __restrict__ nc, int* __restrict__ done,
    int* __restrict__ cand_r, float* __restrict__ cand_d, float* __restrict__ cand_s,
    const float* __restrict__ boxes, float* __restrict__ out) {
  __shared__ float sd[20];
  __shared__ bool s_last;
  const int t = threadIdx.x;
  if (t < 20) sd[t] = dsum[t];
  __syncthreads();

  // ---- phase 1 (all 16 blocks): det-softmax candidate detection ----
  // score <= det_sm, so {det_sm > TH} is a superset of {score > TH}; <=20 rows/class.
  const int r = blockIdx.x * 256 + t;
  for (int c = 0; c < 20; c++) {
    float dsm = fexp(detlog[(size_t)r * 24 + c]) / sd[c];
    if (dsm > SCORE_TH) {
      int p = atomicAdd(&nc[c], 1);
      if (p < 32) { cand_r[c * 32 + p] = r; cand_d[c * 32 + p] = dsm; }
    }
  }
  __threadfence();
  __syncthreads();
  if (t == 0) s_last = (atomicAdd(done, 1) == 15);
  __syncthreads();
  if (!s_last) return;
  __threadfence();

  // ---- phase 2 (last block): exact scores for candidates (cls logits on demand) ----
  for (int slot = t; slot < 640; slot += 256) {
    const int c = slot >> 5, i = slot & 31;
    int n = nc[c]; if (n > 32) n = 32;
    if (i < n) {
      const int rr = cand_r[slot];
      float lg[21];
#pragma unroll
      for (int j = 0; j < 21; j++) lg[j] = b_cls[j];
      const float* xr = x + (size_t)rr * D_N;
      for (int k = 0; k < D_N; k++) {
        float xv = xr[k];
        const float* wr = Wc + (size_t)k * 21;
#pragma unroll
        for (int j = 0; j < 21; j++) lg[j] = fmaf(xv, wr[j], lg[j]);
      }
      float m = -1e30f;
#pragma unroll
      for (int j = 0; j < 21; j++) m = fmaxf(m, lg[j]);
      float s = 0.f;
#pragma unroll
      for (int j = 0; j < 21; j++) s += fexp(lg[j] - m);
      float p = fexp(lg[c] - m) / s;
      cand_s[slot] = p * cand_d[slot];
    }
  }
  __syncthreads();

  // ---- per-class NMS on score>TH candidates ----
  __shared__ int   s_kc;
  __shared__ int   s_ki[512];
  __shared__ float s_ks[512];
  __shared__ float sval[TOPK_N];
  __shared__ int   sidx[TOPK_N];
  if (t == 0) s_kc = 0;
  if (t < TOPK_N) { sval[t] = 0.f; sidx[t] = 0; }
  __syncthreads();

  if (t < 20) {
    const int c = t;
    int n = nc[c]; if (n > 32) n = 32;
    float s[32]; int rr[32]; int n2 = 0;
    for (int i = 0; i < n; i++) {
      float sc = cand_s[c * 32 + i];
      if (sc > SCORE_TH) { s[n2] = sc; rr[n2] = cand_r[c * 32 + i]; n2++; }
    }
    for (int i = 1; i < n2; i++) {                  // score desc, tie -> row asc
      float si = s[i]; int ri = rr[i];
      int j = i - 1;
      while (j >= 0 && (s[j] < si || (s[j] == si && rr[j] > ri))) {
        s[j + 1] = s[j]; rr[j + 1] = rr[j]; j--;
      }
      s[j + 1] = si; rr[j + 1] = ri;
    }
    unsigned supp = 0;
    for (int i = 0; i < n2; i++) {
      if (supp & (1u << i)) continue;
      int g = atomicAdd(&s_kc, 1);
      if (g < 512) { s_ki[g] = rr[i] * C_N + c; s_ks[g] = s[i]; }
      float bi[4]; load_clip_box(boxes, rr[i], bi);
      float ai = (bi[2] - bi[0]) * (bi[3] - bi[1]);
      for (int j = i + 1; j < n2; j++) {
        if (supp & (1u << j)) continue;
        float bj[4]; load_clip_box(boxes, rr[j], bj);
        float aj = (bj[2] - bj[0]) * (bj[3] - bj[1]);
        float lx = fmaxf(bi[0], bj[0]), ly = fmaxf(bi[1], bj[1]);
        float rx = fminf(bi[2], bj[2]), ry = fminf(bi[3], bj[3]);
        float wdt = fmaxf(rx - lx, 0.f), hgt = fmaxf(ry - ly, 0.f);
        float inter = wdt * hgt;
        float iou = inter / (ai + aj - inter + 1e-9f);
        if (iou > NMS_TH) supp |= (1u << j);
      }
    }
  }
  __syncthreads();

  // ---- top-100 with jax.lax.top_k tie rules ----
  int m = s_kc; if (m > 512) m = 512;
  for (int i = t; i < m; i += 256) {
    float si = s_ks[i]; int xi = s_ki[i];
    int rank = 0;
    for (int j = 0; j < m; j++) {
      float sj = s_ks[j]; int xj = s_ki[j];
      if (sj > si || (sj == si && xj < xi)) rank++;
    }
    if (rank < TOPK_N) { sval[rank] = si; sidx[rank] = xi; }
  }
  __syncthreads();
  if (t == 0) {
    int f = m < TOPK_N ? m : TOPK_N;
    int cur = 0;
    for (int slot = f; slot < TOPK_N; slot++) {
      for (;;) {
        bool member = false;
        for (int j = 0; j < m; j++)
          if (s_ki[j] == cur) { member = true; break; }
        if (!member) break;
        cur++;
      }
      sval[slot] = 0.f;
      sidx[slot] = cur;
      cur++;
    }
  }
  __syncthreads();
  if (t < TOPK_N) {
    int idx = sidx[t];
    int prop = idx / C_N;
    int cls = idx - prop * C_N;
    float b[4]; load_clip_box(boxes, prop, b);
    out[t] = sval[t];
    out[TOPK_N + t * 4 + 0] = b[0];
    out[TOPK_N + t * 4 + 1] = b[1];
    out[TOPK_N + t * 4 + 2] = b[2];
    out[TOPK_N + t * 4 + 3] = b[3];
    out[TOPK_N * 5 + t] = (float)cls;
  }
}

extern "C" void kernel_launch(void* const* d_in, const int* in_sizes, int n_in,
                              void* d_out, int out_size, void* d_ws, size_t ws_size,
                              hipStream_t stream) {
  const float* x     = (const float*)d_in[0];
  const float* boxes = (const float*)d_in[1];
  const float* W_cls = (const float*)d_in[2];
  const float* b_cls = (const float*)d_in[3];
  const float* W_det = (const float*)d_in[4];
  // b_det unused: column-softmax bias cancels

  float* out = (float*)d_out;
  float* ws = (float*)d_ws;
  uint4* Wfrag    = (uint4*)ws;
  float* detlog   = ws + DET_OFF;
  float* dsum     = ws + CTRL_OFF;                  // 24 f32
  int*   nc       = (int*)(ws + CTRL_OFF) + 24;     // 20 i32
  int*   done     = (int*)(ws + CTRL_OFF) + 44;     // 1 i32
  int*   cand_r   = (int*)(ws + CAND_R_OFF);
  float* cand_d   = ws + CAND_D_OFF;
  float* cand_s   = ws + CAND_S_OFF;

  wT_kernel     <<<64,  256,  0, stream>>>(W_det, Wfrag, dsum);
  detgemm_kernel<<<256, 1024, 0, stream>>>(x, Wfrag, detlog, dsum);
  finish_kernel <<<16,  256,  0, stream>>>(x, W_cls, b_cls, detlog, dsum,
                                           nc, done, cand_r, cand_d, cand_s,
                                           boxes, out);
}